// Round 8
// baseline (2797.810 us; speedup 1.0000x reference)
//
#include <hip/hip_runtime.h>
#include <hip/hip_bf16.h>

// Problem dims
#define B4 4
#define S128 128
#define T129 129
#define H800 800
#define E256 256
#define NE 66
#define NR 122
#define DPW 8      // LSTM dims per WG
#define NWGD 100   // LSTM WGs per direction

typedef float f32x4 __attribute__((ext_vector_type(4)));

#define HB_ROW 900

// ---------------------------------------------------------------------------
__device__ __forceinline__ float gelu_f(float x) {
    float t = 0.7978845608028654f * (x + 0.044715f * x * x * x);
    float e = __expf(2.f * t);
    float th = 1.f - 2.f / (e + 1.f);
    return 0.5f * x * (1.f + th);
}

// embed(m, c): element of the concatenated input x[516][800], built on the fly
__device__ __forceinline__ float embed_at(const float* __restrict__ bert,
                                          const int* __restrict__ pids,
                                          const float* __restrict__ ptab,
                                          int m, int c)
{
    if (c < 768) return bert[(size_t)m * 768 + c];
    int t = m % T129, b = m / T129;
    if (t == 0) return 0.f;
    return ptab[pids[b * S128 + t - 1] * 32 + (c - 768)];
}

// ---------------------------------------------------------------------------
// Generic fp32 tiled GEMM with register-prefetch pipeline (R5-proven T14).
// AMODE 1: xg-view row. BTRANS 1: A@B^T.
template<int AMODE, int BTRANS, int EPI>
__global__ __launch_bounds__(256) void k_gemm(const float* __restrict__ A, const float* __restrict__ Bm,
                                              const float* __restrict__ bias, const float* __restrict__ res,
                                              float* __restrict__ C, int M, int N, int K)
{
    __shared__ float As[16][68];
    __shared__ float Bs[16][68];
    int m0 = blockIdx.x * 64, n0 = blockIdx.y * 64;
    int tid = threadIdx.x;
    int tm = tid & 15, tn = tid >> 4;
    int kkA = tid & 15, mmb = tid >> 4;       // A-stage coords (also BTRANS=1 B-stage)
    int nnB = (tid & 15) * 4, kkB = tid >> 4; // B-stage coords (BTRANS=0)
    float acc[4][4] = {};
    float aP[4], bP[4];

    // prefetch chunk k0 = 0
    #pragma unroll
    for (int q = 0; q < 4; q++) {
        int m = m0 + mmb + q * 16;
        float v = 0.f;
        if (m < M) {
            int row = (AMODE == 1) ? (m + (m >> 7) + 1) : m;
            v = A[(size_t)row * K + kkA];
        }
        aP[q] = v;
    }
    if (BTRANS == 0) {
        int n = n0 + nnB;
        if (n + 3 < N) {
            float4 bv = *(const float4*)&Bm[(size_t)kkB * N + n];
            bP[0] = bv.x; bP[1] = bv.y; bP[2] = bv.z; bP[3] = bv.w;
        } else {
            #pragma unroll
            for (int q = 0; q < 4; q++)
                bP[q] = (n + q < N) ? Bm[(size_t)kkB * N + n + q] : 0.f;
        }
    } else {
        #pragma unroll
        for (int q = 0; q < 4; q++) {
            int n = n0 + mmb + q * 16;
            bP[q] = (n < N) ? Bm[(size_t)n * K + kkA] : 0.f;
        }
    }

    for (int k0 = 0; k0 < K; k0 += 16) {
        float aC[4], bC[4];
        #pragma unroll
        for (int q = 0; q < 4; q++) { aC[q] = aP[q]; bC[q] = bP[q]; }

        // issue next chunk's loads (clamped; results unused on last iter)
        int kn = (k0 + 16 < K) ? (k0 + 16) : 0;
        #pragma unroll
        for (int q = 0; q < 4; q++) {
            int m = m0 + mmb + q * 16;
            float v = 0.f;
            if (m < M) {
                int row = (AMODE == 1) ? (m + (m >> 7) + 1) : m;
                v = A[(size_t)row * K + kn + kkA];
            }
            aP[q] = v;
        }
        if (BTRANS == 0) {
            int n = n0 + nnB;
            if (n + 3 < N) {
                float4 bv = *(const float4*)&Bm[(size_t)(kn + kkB) * N + n];
                bP[0] = bv.x; bP[1] = bv.y; bP[2] = bv.z; bP[3] = bv.w;
            } else {
                #pragma unroll
                for (int q = 0; q < 4; q++)
                    bP[q] = (n + q < N) ? Bm[(size_t)(kn + kkB) * N + n + q] : 0.f;
            }
        } else {
            #pragma unroll
            for (int q = 0; q < 4; q++) {
                int n = n0 + mmb + q * 16;
                bP[q] = (n < N) ? Bm[(size_t)n * K + kn + kkA] : 0.f;
            }
        }

        // stage current chunk from registers
        #pragma unroll
        for (int q = 0; q < 4; q++)
            As[kkA][mmb + q * 16] = aC[q];
        if (BTRANS == 0) {
            Bs[kkB][nnB + 0] = bC[0]; Bs[kkB][nnB + 1] = bC[1];
            Bs[kkB][nnB + 2] = bC[2]; Bs[kkB][nnB + 3] = bC[3];
        } else {
            #pragma unroll
            for (int q = 0; q < 4; q++)
                Bs[kkA][mmb + q * 16] = bC[q];
        }
        __syncthreads();
        #pragma unroll
        for (int kk = 0; kk < 16; kk++) {
            float4 a = *(const float4*)&As[kk][tm * 4];
            float4 bb = *(const float4*)&Bs[kk][tn * 4];
            float av[4] = {a.x, a.y, a.z, a.w};
            float bv[4] = {bb.x, bb.y, bb.z, bb.w};
            #pragma unroll
            for (int xx = 0; xx < 4; xx++)
                #pragma unroll
                for (int yy = 0; yy < 4; yy++)
                    acc[xx][yy] += av[xx] * bv[yy];
        }
        __syncthreads();
    }
    #pragma unroll
    for (int xx = 0; xx < 4; xx++) {
        int m = m0 + tm * 4 + xx;
        if (m >= M) continue;
        #pragma unroll
        for (int yy = 0; yy < 4; yy++) {
            int n = n0 + tn * 4 + yy;
            if (n >= N) continue;
            float v = acc[xx][yy];
            if (bias) v += bias[n];
            if (EPI == 1) v = res[(size_t)m * N + n] + fmaxf(v, 0.f);
            C[(size_t)m * N + n] = v;
        }
    }
}

// ---------------------------------------------------------------------------
// Merged Wih GEMM with FUSED EMBED A-tile + register-prefetch pipeline:
// C[516][6400] = embed(x) @ [Wih_f | Wih_b]^T + [bl_f | bl_b].
__global__ __launch_bounds__(256) void k_gemm_wih(const float* __restrict__ bert,
                                                  const int* __restrict__ pids,
                                                  const float* __restrict__ ptab,
                                                  const float* __restrict__ Wf, const float* __restrict__ Wb,
                                                  const float* __restrict__ bf, const float* __restrict__ bb_,
                                                  float* __restrict__ C)
{
    __shared__ float As[16][68];
    __shared__ float Bs[16][68];
    const int M = 516, K = 800, N = 6400;
    int m0 = blockIdx.x * 64, n0 = blockIdx.y * 64;
    const float* W  = (n0 < 3200) ? Wf : Wb;
    const float* bi = (n0 < 3200) ? bf : bb_;
    int nb = (n0 < 3200) ? n0 : (n0 - 3200);
    int tid = threadIdx.x;
    int tm = tid & 15, tn = tid >> 4;
    int kk_s = tid & 15, mmb = tid >> 4;
    int mrow[4]; int pofs[4]; bool mok[4];
    #pragma unroll
    for (int q = 0; q < 4; q++) {
        int m = m0 + mmb + q * 16;
        mrow[q] = m;
        mok[q] = m < M;
        int t = m % T129, b = m / T129;
        pofs[q] = (mok[q] && t > 0) ? pids[b * S128 + t - 1] * 32 : -1;
    }
    float acc[4][4] = {};
    float aP[4], bP[4];

    // prefetch chunk k0 = 0
    #pragma unroll
    for (int q = 0; q < 4; q++) {
        float v = 0.f;
        if (mok[q]) {
            if (kk_s < 768) v = bert[(size_t)mrow[q] * 768 + kk_s];
            else            v = (pofs[q] < 0) ? 0.f : ptab[pofs[q] + kk_s - 768];
        }
        aP[q] = v;
    }
    #pragma unroll
    for (int q = 0; q < 4; q++)
        bP[q] = W[(size_t)(nb + mmb + q * 16) * K + kk_s];

    for (int k0 = 0; k0 < K; k0 += 16) {
        float aC[4], bC[4];
        #pragma unroll
        for (int q = 0; q < 4; q++) { aC[q] = aP[q]; bC[q] = bP[q]; }

        int kn = (k0 + 16 < K) ? (k0 + 16) : 0;
        {
            int c = kn + kk_s;
            #pragma unroll
            for (int q = 0; q < 4; q++) {
                float v = 0.f;
                if (mok[q]) {
                    if (c < 768) v = bert[(size_t)mrow[q] * 768 + c];
                    else         v = (pofs[q] < 0) ? 0.f : ptab[pofs[q] + c - 768];
                }
                aP[q] = v;
            }
        }
        #pragma unroll
        for (int q = 0; q < 4; q++)
            bP[q] = W[(size_t)(nb + mmb + q * 16) * K + kn + kk_s];

        #pragma unroll
        for (int q = 0; q < 4; q++)
            As[kk_s][mmb + q * 16] = aC[q];
        #pragma unroll
        for (int q = 0; q < 4; q++)
            Bs[kk_s][mmb + q * 16] = bC[q];
        __syncthreads();
        #pragma unroll
        for (int kk = 0; kk < 16; kk++) {
            float4 a = *(const float4*)&As[kk][tm * 4];
            float4 bb = *(const float4*)&Bs[kk][tn * 4];
            float av[4] = {a.x, a.y, a.z, a.w};
            float bv[4] = {bb.x, bb.y, bb.z, bb.w};
            #pragma unroll
            for (int xx = 0; xx < 4; xx++)
                #pragma unroll
                for (int yy = 0; yy < 4; yy++)
                    acc[xx][yy] += av[xx] * bv[yy];
        }
        __syncthreads();
    }
    #pragma unroll
    for (int xx = 0; xx < 4; xx++) {
        int m = m0 + tm * 4 + xx;
        if (m >= M) continue;
        #pragma unroll
        for (int yy = 0; yy < 4; yy++) {
            int n = n0 + tn * 4 + yy;
            C[(size_t)m * N + n] = acc[xx][yy] + bi[nb + (n - n0)];
        }
    }
}

// ---------------------------------------------------------------------------
// fc GEMM with FUSED EMBED residual + register-prefetch pipeline:
// xg = embed(x) + relu(lstm @ fcW + fcb).
__global__ __launch_bounds__(256) void k_gemm_fc(const float* __restrict__ A, const float* __restrict__ Bm,
                                                 const float* __restrict__ bias,
                                                 const float* __restrict__ bert, const int* __restrict__ pids,
                                                 const float* __restrict__ ptab, float* __restrict__ C)
{
    __shared__ float As[16][68];
    __shared__ float Bs[16][68];
    const int M = 516, N = 800, K = 1600;
    int m0 = blockIdx.x * 64, n0 = blockIdx.y * 64;
    int tid = threadIdx.x;
    int tm = tid & 15, tn = tid >> 4;
    int kkA = tid & 15, mmb = tid >> 4;
    int nnB = (tid & 15) * 4, kkB = tid >> 4;
    float acc[4][4] = {};
    float aP[4], bP[4];

    // prefetch chunk k0 = 0
    #pragma unroll
    for (int q = 0; q < 4; q++) {
        int m = m0 + mmb + q * 16;
        aP[q] = (m < M) ? A[(size_t)m * K + kkA] : 0.f;
    }
    {
        int n = n0 + nnB;
        if (n + 3 < N) {
            float4 bv = *(const float4*)&Bm[(size_t)kkB * N + n];
            bP[0] = bv.x; bP[1] = bv.y; bP[2] = bv.z; bP[3] = bv.w;
        } else {
            #pragma unroll
            for (int q = 0; q < 4; q++)
                bP[q] = (n + q < N) ? Bm[(size_t)kkB * N + n + q] : 0.f;
        }
    }

    for (int k0 = 0; k0 < K; k0 += 16) {
        float aC[4], bC[4];
        #pragma unroll
        for (int q = 0; q < 4; q++) { aC[q] = aP[q]; bC[q] = bP[q]; }

        int kn = (k0 + 16 < K) ? (k0 + 16) : 0;
        #pragma unroll
        for (int q = 0; q < 4; q++) {
            int m = m0 + mmb + q * 16;
            aP[q] = (m < M) ? A[(size_t)m * K + kn + kkA] : 0.f;
        }
        {
            int n = n0 + nnB;
            if (n + 3 < N) {
                float4 bv = *(const float4*)&Bm[(size_t)(kn + kkB) * N + n];
                bP[0] = bv.x; bP[1] = bv.y; bP[2] = bv.z; bP[3] = bv.w;
            } else {
                #pragma unroll
                for (int q = 0; q < 4; q++)
                    bP[q] = (n + q < N) ? Bm[(size_t)(kn + kkB) * N + n + q] : 0.f;
            }
        }

        #pragma unroll
        for (int q = 0; q < 4; q++)
            As[kkA][mmb + q * 16] = aC[q];
        Bs[kkB][nnB + 0] = bC[0]; Bs[kkB][nnB + 1] = bC[1];
        Bs[kkB][nnB + 2] = bC[2]; Bs[kkB][nnB + 3] = bC[3];
        __syncthreads();
        #pragma unroll
        for (int kk = 0; kk < 16; kk++) {
            float4 a = *(const float4*)&As[kk][tm * 4];
            float4 bb = *(const float4*)&Bs[kk][tn * 4];
            float av[4] = {a.x, a.y, a.z, a.w};
            float bv[4] = {bb.x, bb.y, bb.z, bb.w};
            #pragma unroll
            for (int xx = 0; xx < 4; xx++)
                #pragma unroll
                for (int yy = 0; yy < 4; yy++)
                    acc[xx][yy] += av[xx] * bv[yy];
        }
        __syncthreads();
    }
    #pragma unroll
    for (int xx = 0; xx < 4; xx++) {
        int m = m0 + tm * 4 + xx;
        if (m >= M) continue;
        #pragma unroll
        for (int yy = 0; yy < 4; yy++) {
            int n = n0 + tn * 4 + yy;
            if (n >= N) continue;
            float v = fmaxf(acc[xx][yy] + bias[n], 0.f);
            C[(size_t)m * N + n] = embed_at(bert, pids, ptab, m, n) + v;
        }
    }
}

// ---------------------------------------------------------------------------
// Merged table GEMM + register-prefetch pipeline:
// uv[512][1600]; col n<800: g2@tW[:800] + tb; else g2@tW[800:].
__global__ __launch_bounds__(256) void k_gemm_uv(const float* __restrict__ A, const float* __restrict__ tW,
                                                 const float* __restrict__ tb, float* __restrict__ C)
{
    __shared__ float As[16][68];
    __shared__ float Bs[16][68];
    const int M = 512, K = 800, N = 1600;
    int m0 = blockIdx.x * 64, n0 = blockIdx.y * 64;
    int tid = threadIdx.x;
    int tm = tid & 15, tn = tid >> 4;
    int kkA = tid & 15, mmb = tid >> 4;
    int nnB = (tid & 15) * 4, kkB = tid >> 4;
    float acc[4][4] = {};
    float aP[4], bP[4];

    // prefetch chunk k0 = 0
    #pragma unroll
    for (int q = 0; q < 4; q++)
        aP[q] = A[(size_t)(m0 + mmb + q * 16) * K + kkA];
    #pragma unroll
    for (int q = 0; q < 4; q++) {
        int n = n0 + nnB + q;
        bP[q] = (n < 800) ? tW[(size_t)kkB * 800 + n]
                          : tW[(size_t)(800 + kkB) * 800 + (n - 800)];
    }

    for (int k0 = 0; k0 < K; k0 += 16) {
        float aC[4], bC[4];
        #pragma unroll
        for (int q = 0; q < 4; q++) { aC[q] = aP[q]; bC[q] = bP[q]; }

        int kn = (k0 + 16 < K) ? (k0 + 16) : 0;
        #pragma unroll
        for (int q = 0; q < 4; q++)
            aP[q] = A[(size_t)(m0 + mmb + q * 16) * K + kn + kkA];
        #pragma unroll
        for (int q = 0; q < 4; q++) {
            int n = n0 + nnB + q;
            bP[q] = (n < 800) ? tW[(size_t)(kn + kkB) * 800 + n]
                              : tW[(size_t)(800 + kn + kkB) * 800 + (n - 800)];
        }

        #pragma unroll
        for (int q = 0; q < 4; q++)
            As[kkA][mmb + q * 16] = aC[q];
        #pragma unroll
        for (int q = 0; q < 4; q++)
            Bs[kkB][nnB + q] = bC[q];
        __syncthreads();
        #pragma unroll
        for (int kk = 0; kk < 16; kk++) {
            float4 a = *(const float4*)&As[kk][tm * 4];
            float4 bb = *(const float4*)&Bs[kk][tn * 4];
            float av[4] = {a.x, a.y, a.z, a.w};
            float bv[4] = {bb.x, bb.y, bb.z, bb.w};
            #pragma unroll
            for (int xx = 0; xx < 4; xx++)
                #pragma unroll
                for (int yy = 0; yy < 4; yy++)
                    acc[xx][yy] += av[xx] * bv[yy];
        }
        __syncthreads();
    }
    #pragma unroll
    for (int xx = 0; xx < 4; xx++) {
        int m = m0 + tm * 4 + xx;
        #pragma unroll
        for (int yy = 0; yy < 4; yy++) {
            int n = n0 + tn * 4 + yy;
            float v = acc[xx][yy];
            if (n < 800) v += tb[n];
            C[(size_t)m * N + n] = v;
        }
    }
}

// ---------------------------------------------------------------------------
// Persistent BiLSTM v11 (BEST-KNOWN, reverted from v12):
//  - hpk pre-filled with 0x7F bytes (float 3.39e38 sentinel) each launch.
//  - LSTM h in (-1,1): a granule whose 4 floats are all |v| < 1.5 is real
//    data. Each 16B granule is one lane's single global_store_dwordx4
//    (committed as a unit) -> no torn-granule hazard.
//  - consumers poll the DATA granules directly: the poll load IS the data
//    load (no flag hop, no detect->load serialization).
//  - v12's light-detect and merged wave0 reduce both REGRESSED (r3:
//    +50us, 4x LDS bank conflicts) -> reverted.
__global__ __launch_bounds__(256) void k_lstm(const float* __restrict__ xW,
                                              const float* __restrict__ Whhf, const float* __restrict__ Whhb,
                                              float* __restrict__ lstm, float* __restrict__ hpk)
{
    __shared__ float hb[4][HB_ROW];     // staggered h_{t-1}
    __shared__ float gsum[25][32][4];   // [slice][g*8+d][b]
    __shared__ float gg[128];           // reduced gates: idx (g<<5)|(d<<2)|b
    int wg = blockIdx.x;
    int dir = wg >= NWGD ? 1 : 0;
    int wgd = dir ? wg - NWGD : wg;
    const float* Whh = dir ? Whhb : Whhf;
    const float* xWd = xW + dir * 3200;
    int tid = threadIdx.x;
    bool dotth = tid < 200;
    int d = tid & 7, sl = tid >> 3;     // valid for dotth (sl 0..24)
    int k0 = sl * 32;
    int rb = tid & 3, rd = (tid >> 2) & 7, rg = tid >> 5;
    int lane = tid & 63;

    float wreg[4][32];
    if (dotth) {
        #pragma unroll
        for (int g = 0; g < 4; g++) {
            const float* wp = Whh + (size_t)(g * 800 + wgd * DPW + d) * 800 + k0;
            #pragma unroll
            for (int q = 0; q < 32; q += 4)
                *(float4*)&wreg[g][q] = *(const float4*)&wp[q];
        }
    }
    for (int i = tid; i < 4 * HB_ROW; i += 256) (&hb[0][0])[i] = 0.f;
    __syncthreads();

    float cst = 0.f;                    // cell state (tid<32)

    for (int step = 0; step < 129; step++) {
        int t = dir ? (128 - step) : step;
        float xq = 0.f;
        if (tid < 128)
            xq = xWd[(size_t)(rb * T129 + t) * 6400 + rg * 800 + wgd * DPW + rd];
        if (step > 0) {
            int tprev = dir ? (t + 1) : (t - 1);
            if (tid < 200) {
                const f32x4* pb = (const f32x4*)(hpk + (size_t)(dir * 129 + tprev) * 3200);
                const f32x4* p0 = pb + tid;
                const f32x4* p1 = pb + tid + 200;
                const f32x4* p2 = pb + tid + 400;
                const f32x4* p3 = pb + tid + 600;
                f32x4 v0, v1, v2, v3;
                long long iters = 0;
                for (;;) {
                    asm volatile(
                        "global_load_dwordx4 %0, %4, off sc0 sc1\n\t"
                        "global_load_dwordx4 %1, %5, off sc0 sc1\n\t"
                        "global_load_dwordx4 %2, %6, off sc0 sc1\n\t"
                        "global_load_dwordx4 %3, %7, off sc0 sc1\n\t"
                        "s_waitcnt vmcnt(0)"
                        : "=&v"(v0), "=&v"(v1), "=&v"(v2), "=&v"(v3)
                        : "v"(p0), "v"(p1), "v"(p2), "v"(p3)
                        : "memory");
                    bool ok = fabsf(v0.x) < 1.5f && fabsf(v0.y) < 1.5f &&
                              fabsf(v0.z) < 1.5f && fabsf(v0.w) < 1.5f &&
                              fabsf(v1.x) < 1.5f && fabsf(v1.y) < 1.5f &&
                              fabsf(v1.z) < 1.5f && fabsf(v1.w) < 1.5f &&
                              fabsf(v2.x) < 1.5f && fabsf(v2.y) < 1.5f &&
                              fabsf(v2.z) < 1.5f && fabsf(v2.w) < 1.5f &&
                              fabsf(v3.x) < 1.5f && fabsf(v3.y) < 1.5f &&
                              fabsf(v3.z) < 1.5f && fabsf(v3.w) < 1.5f;
                    if (ok) break;
                    if (++iters > 20000000LL) break;
                }
                // packed slot s (f32x4 index in [0,800)):
                //   wg = s>>3, b = (s&7)>>1, d0 = (s&1)*4, dim p = wg*8+d0
                //   staggered hb slot = b*225 + (p>>5)*9 + ((p&31)>>2)
                {
                    int s0 = tid;
                    int p_ = (s0 >> 3) * 8 + (s0 & 1) * 4;
                    ((f32x4*)&hb[0][0])[((s0 & 7) >> 1) * 225 + (p_ >> 5) * 9 + ((p_ & 31) >> 2)] = v0;
                }
                {
                    int s1 = tid + 200;
                    int p_ = (s1 >> 3) * 8 + (s1 & 1) * 4;
                    ((f32x4*)&hb[0][0])[((s1 & 7) >> 1) * 225 + (p_ >> 5) * 9 + ((p_ & 31) >> 2)] = v1;
                }
                {
                    int s2 = tid + 400;
                    int p_ = (s2 >> 3) * 8 + (s2 & 1) * 4;
                    ((f32x4*)&hb[0][0])[((s2 & 7) >> 1) * 225 + (p_ >> 5) * 9 + ((p_ & 31) >> 2)] = v2;
                }
                {
                    int s3 = tid + 600;
                    int p_ = (s3 >> 3) * 8 + (s3 & 1) * 4;
                    ((f32x4*)&hb[0][0])[((s3 & 7) >> 1) * 225 + (p_ >> 5) * 9 + ((p_ & 31) >> 2)] = v3;
                }
            }
            __syncthreads();
        }
        if (dotth) {
            float a[4][4] = {};   // [gate][batch]
            #pragma unroll
            for (int b = 0; b < 4; b++) {
                const float* hrow = &hb[b][0];
                #pragma unroll
                for (int q = 0; q < 32; q += 4) {
                    float4 h = *(const float4*)&hrow[sl * 36 + q];
                    #pragma unroll
                    for (int g = 0; g < 4; g++)
                        a[g][b] += wreg[g][q] * h.x + wreg[g][q + 1] * h.y
                                 + wreg[g][q + 2] * h.z + wreg[g][q + 3] * h.w;
                }
            }
            #pragma unroll
            for (int g = 0; g < 4; g++)
                *(float4*)&gsum[sl][g * 8 + d][0] = make_float4(a[g][0], a[g][1], a[g][2], a[g][3]);
        }
        __syncthreads();
        if (tid < 128) {
            float s = xq;
            #pragma unroll
            for (int ss = 0; ss < 25; ss++) s += gsum[ss][rg * 8 + rd][rb];
            gg[tid] = s;
        }
        __syncthreads();
        float hv = 0.f;
        if (tid < 32) {
            int dd = tid & 7, bb2 = tid >> 3;
            float gi = gg[(0 << 5) | (dd << 2) | bb2];
            float gf = gg[(1 << 5) | (dd << 2) | bb2];
            float gG = gg[(2 << 5) | (dd << 2) | bb2];
            float go = gg[(3 << 5) | (dd << 2) | bb2];
            float si = 1.f / (1.f + __expf(-gi));
            float sf = 1.f / (1.f + __expf(-gf));
            float so = 1.f / (1.f + __expf(-go));
            cst = sf * cst + si * tanhf(gG);
            hv = so * tanhf(cst);
        }
        if (tid < 64) {
            int src = (lane & 7) * 4;
            f32x4 o;
            o.x = __shfl(hv, src + 0, 64);
            o.y = __shfl(hv, src + 1, 64);
            o.z = __shfl(hv, src + 2, 64);
            o.w = __shfl(hv, src + 3, 64);
            // packed publish: lane l -> r = 4*l .. 4*l+3 of this WG's 32-float line.
            // No vmcnt, no flag: validity is in-band (|h| < 1).
            if (lane < 8) {
                float* pp = hpk + ((size_t)(dir * 129 + t) * 100 + wgd) * 32 + lane * 4;
                asm volatile("global_store_dwordx4 %0, %1, off sc0 sc1"
                             :: "v"((f32x4*)pp), "v"(o) : "memory");
            }
            // standard-layout store for k_gemm_fc (post-kernel consumer):
            // off the critical path, fire-and-forget.
            if (lane < 8) {
                int bb = lane >> 1, half = lane & 1;
                float* ap = lstm + (size_t)((bb * T129 + t) * 1600) + dir * 800 + wgd * DPW + half * 4;
                asm volatile("global_store_dwordx4 %0, %1, off sc0 sc1"
                             :: "v"((f32x4*)ap), "v"(o) : "memory");
            }
        }
    }
}

// ---------------------------------------------------------------------------
// Fused GAT layer (coef + softmax + aggregate), one block per (b,h).
template<int RESMODE>
__global__ __launch_bounds__(512) void k_gat_fused(const int* __restrict__ esrc, const int* __restrict__ edst,
                                                   const float* __restrict__ h1,
                                                   const float* __restrict__ asrc, const float* __restrict__ adst,
                                                   const float* __restrict__ gbias,
                                                   const float* __restrict__ res, float* __restrict__ out)
{
    __shared__ int se[384], de[384];
    __shared__ float asl[128], adl[128], ml[128], dl_[128];
    int bh = blockIdx.x;
    int b = bh >> 3, h = bh & 7;
    int t = threadIdx.x;
    if (t < 384) {
        if (t < E256) { se[t] = esrc[b * E256 + t]; de[t] = edst[b * E256 + t]; }
        else          { se[t] = t - E256;           de[t] = t - E256; }
    }
    int node = t >> 2, ch = t & 3;
    int dd0 = ch * 25;
    {
        const float* hp = h1 + (size_t)(b * S128 + node) * H800 + h * 100 + dd0;
        const float* ap = asrc + h * 100 + dd0;
        const float* dp = adst + h * 100 + dd0;
        float s1 = 0.f, s2 = 0.f;
        #pragma unroll
        for (int q = 0; q < 25; q++) { float hv = hp[q]; s1 += hv * ap[q]; s2 += hv * dp[q]; }
        s1 += __shfl_xor(s1, 1, 64); s1 += __shfl_xor(s1, 2, 64);
        s2 += __shfl_xor(s2, 1, 64); s2 += __shfl_xor(s2, 2, 64);
        if (ch == 0) { asl[node] = s1; adl[node] = s2; }
    }
    __syncthreads();
    if (t < 128) {
        float myad = adl[t];
        float m = -3.4e38f;
        for (int e = 0; e < 384; e++)
            if (de[e] == t) {
                float sc = asl[se[e]] + myad;
                sc = (sc > 0.f) ? sc : 0.2f * sc;
                m = fmaxf(m, sc);
            }
        float den = 0.f;
        for (int e = 0; e < 384; e++)
            if (de[e] == t) {
                float sc = asl[se[e]] + myad;
                sc = (sc > 0.f) ? sc : 0.2f * sc;
                den += __expf(sc - m);
            }
        ml[t] = m; dl_[t] = den;
    }
    __syncthreads();
    float acc[25] = {};
    float myad = adl[node], mym = ml[node];
    for (int e = 0; e < 384; e++) {
        if (de[e] == node) {
            int s = se[e];
            float sc = asl[s] + myad;
            sc = (sc > 0.f) ? sc : 0.2f * sc;
            float w = __expf(sc - mym);
            const float* hp = h1 + (size_t)(b * S128 + s) * H800 + h * 100 + dd0;
            #pragma unroll
            for (int q = 0; q < 25; q++) acc[q] += w * hp[q];
        }
    }
    float inv = 1.f / dl_[node];
    int n = b * S128 + node;
    size_t rrow = (RESMODE == 1) ? (size_t)(n + b + 1) * H800 : (size_t)n * H800;
    #pragma unroll
    for (int q = 0; q < 25; q++) {
        int col = h * 100 + dd0 + q;
        float v = acc[q] * inv + gbias[col];
        out[(size_t)n * H800 + col] = res[rrow + col] + fmaxf(v, 0.f);
    }
}

// ---------------------------------------------------------------------------
// Trig head, diagonal only. uv stride 1600: u = row, v = row+800.
__global__ __launch_bounds__(64) void k_trig(const float* __restrict__ uv,
                                             const float* __restrict__ W, const float* __restrict__ bias,
                                             const int* __restrict__ labels, float* __restrict__ d_out)
{
    __shared__ float s[800];
    __shared__ float lg[66];
    int bi = blockIdx.x;          // b*128+i
    int i = bi & 127;
    int l = threadIdx.x;
    const float* ur = uv + (size_t)bi * 1600;
    const float* vr = ur + 800;
    for (int k = l; k < 800; k += 64) s[k] = gelu_f(ur[k] + vr[k]);
    __syncthreads();
    float a0 = 0.f, a1 = 0.f;
    bool has2 = (l < 2);
    for (int k = 0; k < 800; k++) {
        float sv = s[k];
        a0 += sv * W[k * NE + l];
        if (has2) a1 += sv * W[k * NE + 64 + l];
    }
    lg[l] = a0 + bias[l];
    if (has2) lg[64 + l] = a1 + bias[64 + l];
    __syncthreads();
    if (l == 0) {
        float m = lg[0];
        for (int c = 1; c < NE; c++) m = fmaxf(m, lg[c]);
        float se = 0.f, sl = 0.f, bv = lg[0];
        int am = 0;
        for (int c = 0; c < NE; c++) {
            se += __expf(lg[c] - m);
            sl += lg[c];
            if (lg[c] > bv) { bv = lg[c]; am = c; }
        }
        float lse = m + __logf(se);
        int tgt = labels[(size_t)bi * S128 + i];
        float ce = (0.1f / NE) * (NE * lse - sl) + 0.9f * (lse - lg[tgt]);
        atomicAdd(d_out, ce * (1.f / 128.f));
        int r = bi * S128 + i;
        d_out[1 + r] = (float)am;
        d_out[1 + 65536 + r] = (float)am;
    }
}

// ---------------------------------------------------------------------------
// Fused rs+re logits, NB batches per launch (blockIdx.y). uv stride 1600.
// v4: 128x256 output tile per block (one il per block), 8x16 per thread.
//  - R7 post-mortem: the kernel is LDS-THROUGHPUT-bound (ds_read_b128 ~12
//    cyc/CU, m134): 8x8 tile = 4 b128-reads/64 FMA -> 14.2K LDS cyc vs 8.3K
//    VALU cyc per CU per chunk. 8x16 = 6 b128/128 FMA (0.75x), and half the
//    blocks halves Bs-write + W-L2 traffic.
//  - A stored with +4-words-per-8-rows pad: word = r + ((r>>3)<<2). The 8
//    rows a thread reads are contiguous at word tm*12 (16B-aligned, two
//    b128), and the 16 group bases alias banks 2-way (free, m136) instead
//    of the 4-way a linear layout would give.
//  - Bs remains wave-private (wave w covers cols [64w,64w+64)); single
//    barrier per chunk (R7 scheme); register prefetch W+1 / u,v+2.
__global__ __launch_bounds__(256, 2) void k_logits2(const float* __restrict__ uvb,
                                                 const float* __restrict__ rsW, const float* __restrict__ rsb,
                                                 const float* __restrict__ reW, const float* __restrict__ reb,
                                                 float* __restrict__ L)
{
    __shared__ float As[2][16][192];    // swizzled row word: r + ((r>>3)<<2), max 187
    __shared__ float Bs[4][16][68];     // per-wave col slice
    int bi = blockIdx.y;
    const float* base = uvb + (size_t)bi * 128 * 1600;
    float* Lb = L + (size_t)bi * 16384 * 256;
    int il = blockIdx.x;
    const float* urow = base + (size_t)il * 1600;
    int tid = threadIdx.x;
    int wv = tid >> 6, lane = tid & 63;
    int tm = tid & 15, tn = tid >> 4;       // rows tm*8..+7, cols tn*16..+15
    int cln = (lane >> 4) * 16;             // within-wave col offset
    float acc[8][16] = {};
    int hc = (tid < 128) ? tid : (tid - 128);
    const float* Wp = (tid < 128) ? rsW : reW;
    bool cok = hc < NR;
    int kk = tid & 15, rrb = tid >> 4;      // staging: k=kk, rows rrb+q*16

    // --- prologue ---
    float u0 = urow[kk];
    float v0q[8];
    #pragma unroll
    for (int q = 0; q < 8; q++)
        v0q[q] = base[(size_t)(rrb + q * 16) * 1600 + 800 + kk];
    float wP[16];
    #pragma unroll
    for (int kk2 = 0; kk2 < 16; kk2++)
        wP[kk2] = cok ? Wp[(size_t)kk2 * NR + hc] : 0.f;
    float uP = urow[16 + kk];
    float vP[8];
    #pragma unroll
    for (int q = 0; q < 8; q++)
        vP[q] = base[(size_t)(rrb + q * 16) * 1600 + 800 + 16 + kk];

    // stage As[0] (chunk 0)
    #pragma unroll
    for (int q = 0; q < 8; q++) {
        int r = rrb + q * 16;
        As[0][kk][r + ((r >> 3) << 2)] = gelu_f(u0 + v0q[q]);
    }
    __syncthreads();

    for (int c = 0; c < 50; ++c) {
        // stage Bs (chunk c) -- wave-private, no barrier needed
        #pragma unroll
        for (int kk2 = 0; kk2 < 16; kk2++)
            Bs[wv][kk2][lane] = wP[kk2];
        // stage As[(c+1)&1] (chunk c+1)
        #pragma unroll
        for (int q = 0; q < 8; q++) {
            int r = rrb + q * 16;
            As[(c + 1) & 1][kk][r + ((r >> 3) << 2)] = gelu_f(uP + vP[q]);
        }
        // prefetch: W <- chunk c+1, u/v <- chunk c+2 (clamped)
        int k1 = (c + 1 < 50) ? (c + 1) * 16 : 0;
        int k2 = (c + 2 < 50) ? (c + 2) * 16 : 0;
        #pragma unroll
        for (int kk2 = 0; kk2 < 16; kk2++)
            wP[kk2] = cok ? Wp[(size_t)(k1 + kk2) * NR + hc] : 0.f;
        uP = urow[k2 + kk];
        #pragma unroll
        for (int q = 0; q < 8; q++)
            vP[q] = base[(size_t)(rrb + q * 16) * 1600 + 800 + k2 + kk];

        // compute chunk c from As[c&1] + this wave's Bs slice
        const float (*Ac)[192] = As[c & 1];
        #pragma unroll
        for (int kki = 0; kki < 16; kki++) {
            float4 a0 = *(const float4*)&Ac[kki][tm * 12];
            float4 a1 = *(const float4*)&Ac[kki][tm * 12 + 4];
            float4 b0 = *(const float4*)&Bs[wv][kki][cln];
            float4 b1 = *(const float4*)&Bs[wv][kki][cln + 4];
            float4 b2 = *(const float4*)&Bs[wv][kki][cln + 8];
            float4 b3 = *(const float4*)&Bs[wv][kki][cln + 12];
            float av[8]  = {a0.x, a0.y, a0.z, a0.w, a1.x, a1.y, a1.z, a1.w};
            float bvv[16] = {b0.x, b0.y, b0.z, b0.w, b1.x, b1.y, b1.z, b1.w,
                             b2.x, b2.y, b2.z, b2.w, b3.x, b3.y, b3.z, b3.w};
            #pragma unroll
            for (int xx = 0; xx < 8; xx++)
                #pragma unroll
                for (int yy = 0; yy < 16; yy++)
                    acc[xx][yy] += av[xx] * bvv[yy];
        }
        __syncthreads();
    }
    // epilogue: rows il*128 + tm*8+xx, cols tn*16+yy (all 16 same head)
    const float* bp = (tn >= 8) ? reb : rsb;
    #pragma unroll
    for (int xx = 0; xx < 8; xx++) {
        int r = il * S128 + tm * 8 + xx;
        float* Lr = Lb + (size_t)r * 256 + tn * 16;
        #pragma unroll
        for (int hf = 0; hf < 4; hf++) {
            int cb = (tn * 16 + hf * 4) & 127;
            if (cb + 3 < NR) {
                float4 o = make_float4(acc[xx][hf*4+0] + bp[cb+0], acc[xx][hf*4+1] + bp[cb+1],
                                       acc[xx][hf*4+2] + bp[cb+2], acc[xx][hf*4+3] + bp[cb+3]);
                *(float4*)(Lr + hf * 4) = o;
            } else {
                #pragma unroll
                for (int q = 0; q < 4; q++)
                    if (cb + q < NR) Lr[hf * 4 + q] = acc[xx][hf*4+q] + bp[cb+q];
            }
        }
    }
}

// CE loss + symmetric argmax, both heads. Handles any number of batches via
// grid size: rr in [0, nbatch*16384), bi = rr>>14 indexes L/labels/results.
__global__ __launch_bounds__(256) void k_loss2(const float* __restrict__ L,
                                               const int* __restrict__ lab0, const int* __restrict__ lab1,
                                               float* __restrict__ res0, float* __restrict__ res1,
                                               float* __restrict__ lossptr)
{
    __shared__ float wsum[4];
    int wv = threadIdx.x >> 6, l = threadIdx.x & 63;
    int rr = blockIdx.x * 4 + wv;
    int bi = rr >> 14;
    int r = rr & 16383;
    int i = r >> 7, j = r & 127;
    size_t bioff = (size_t)bi * 16384;
    float ces = 0.f;
    if (i != j) {
        const float* row  = L + (bioff + r) * 256;
        const float* prow = L + (bioff + ((j << 7) | i)) * 256;
        bool v2 = (l < NR - 64);
        #pragma unroll
        for (int hd = 0; hd < 2; hd++) {
            const float* rw = row + hd * 128;
            const float* pw = prow + hd * 128;
            float x1 = rw[l];
            float x2 = v2 ? rw[l + 64] : -3.4e38f;
            float m = fmaxf(x1, x2);
            #pragma unroll
            for (int s = 32; s; s >>= 1) m = fmaxf(m, __shfl_xor(m, s, 64));
            float se = __expf(x1 - m) + (v2 ? __expf(x2 - m) : 0.f);
            float sl = x1 + (v2 ? x2 : 0.f);
            #pragma unroll
            for (int s = 32; s; s >>= 1) { se += __shfl_xor(se, s, 64); sl += __shfl_xor(sl, s, 64); }
            float lse = m + __logf(se);
            int tgt = (hd ? lab1 : lab0)[bioff + r];
            float lt = rw[tgt];
            ces += (0.1f / NR) * (NR * lse - sl) + 0.9f * (lse - lt);
            float y1 = x1 + pw[l];
            float y2 = v2 ? (x2 + pw[l + 64]) : -3.4e38f;
            float bv; int bidx;
            if (y2 > y1) { bv = y2; bidx = l + 64; } else { bv = y1; bidx = l; }
            #pragma unroll
            for (int s = 32; s; s >>= 1) {
                float ov = __shfl_xor(bv, s, 64);
                int oi = __shfl_xor(bidx, s, 64);
                if (ov > bv || (ov == bv && oi < bidx)) { bv = ov; bidx = oi; }
            }
            if (l == 0) (hd ? res1 : res0)[bioff + r] = (float)bidx;
        }
    }
    if (l == 0) wsum[wv] = ces;
    __syncthreads();
    if (threadIdx.x == 0) {
        float s = (wsum[0] + wsum[1] + wsum[2] + wsum[3]) * (1.f / 16256.f);
        atomicAdd(lossptr, s);
    }
}

// ---------------------------------------------------------------------------
extern "C" void kernel_launch(void* const* d_in, const int* in_sizes, int n_in,
                              void* d_out, int out_size, void* d_ws, size_t ws_size,
                              hipStream_t stream)
{
    (void)in_sizes; (void)n_in; (void)out_size;
    const float* bert  = (const float*)d_in[0];
    const int*   pids  = (const int*)d_in[1];
    const int*   esrc  = (const int*)d_in[2];
    const int*   edst  = (const int*)d_in[3];
    const int*   slab  = (const int*)d_in[4];
    const int*   elab  = (const int*)d_in[5];
    const float* ptab  = (const float*)d_in[6];
    const float* Wih_f = (const float*)d_in[7];
    const float* Whh_f = (const float*)d_in[8];
    const float* bl_f  = (const float*)d_in[9];
    const float* Wih_b = (const float*)d_in[10];
    const float* Whh_b = (const float*)d_in[11];
    const float* bl_b  = (const float*)d_in[12];
    const float* fcW   = (const float*)d_in[13];
    const float* fcb   = (const float*)d_in[14];
    const float* tW    = (const float*)d_in[15];
    const float* tb    = (const float*)d_in[16];
    const float* gatW  = (const float*)d_in[17];
    const float* asrc  = (const float*)d_in[18];
    const float* adst  = (const float*)d_in[19];
    const float* gbias = (const float*)d_in[20];
    const float* trigW = (const float*)d_in[21];
    const float* trigb = (const float*)d_in[22];
    const float* rsW   = (const float*)d_in[23];
    const float* rsb   = (const float*)d_in[24];
    const float* reW   = (const float*)d_in[25];
    const float* reb   = (const float*)d_in[26];
    float* out = (float*)d_out;

    float* ws = (float*)d_ws;
    size_t off = 0;
    auto alloc = [&](size_t n) { float* p = ws + off; off += (n + 255) & ~(size_t)255; return p; };
    float* uv    = alloc((size_t)512 * 1600);     // live late (trig/logits)
    float* R     = ws + off;                      // overlay region
    size_t roff = 0;
    auto ralloc = [&](size_t n) { float* p = R + roff; roff += (n + 255) & ~(size_t)255; return p; };
    float* xW   = ralloc((size_t)516 * 6400);
    float* lstm = ralloc((size_t)516 * 1600);
    float* xg   = ralloc(516 * 800);
    float* h1   = ralloc(512 * 800);
    float* g1   = ralloc(512 * 800);
    float* g2   = ralloc(512 * 800);
    float* hpk  = ralloc((size_t)2 * 129 * 100 * 32);  // packed h exchange; dead before Lbuf
    float* Lbuf = R;   // overlays dead temps

    hipMemsetAsync(d_out, 0, 4, stream);                 // loss accumulator
    // sentinel-fill the h exchange: 0x7F7F7F7F = 3.39e38 (|v| >= 1.5 => not yet written).
    // Stream-ordered before k_lstm, so workspace poison can never look valid.
    hipMemsetAsync(hpk, 0x7F, (size_t)2 * 129 * 100 * 32 * sizeof(float), stream);

    // merged gate-input precompute with fused embed
    k_gemm_wih<<<dim3(9, 100), 256, 0, stream>>>(bert, pids, ptab, Wih_f, Wih_b, bl_f, bl_b, xW);

    k_lstm<<<2 * NWGD, 256, 0, stream>>>(xW, Whh_f, Whh_b, lstm, hpk);

    // xg = embed(x) + relu(lstm @ fcW + fcb)
    k_gemm_fc<<<dim3(9, 13), 256, 0, stream>>>(lstm, fcW, fcb, bert, pids, ptab, xg);

    // GAT layer 1 (input = xg[:,1:,:] view)
    k_gemm<1, 0, 0><<<dim3(8, 13), 256, 0, stream>>>(xg, gatW, nullptr, nullptr, h1, 512, 800, 800);
    k_gat_fused<1><<<32, 512, 0, stream>>>(esrc, edst, h1, asrc, adst, gbias, xg, g1);
    // GAT layer 2
    k_gemm<0, 0, 0><<<dim3(8, 13), 256, 0, stream>>>(g1, gatW, nullptr, nullptr, h1, 512, 800, 800);
    k_gat_fused<0><<<32, 512, 0, stream>>>(esrc, edst, h1, asrc, adst, gbias, g1, g2);

    // merged table split: uv[512][1600] (u | v)
    k_gemm_uv<<<dim3(8, 25), 256, 0, stream>>>(g2, tW, tb, uv);

    // trig head (diag)
    k_trig<<<512, 64, 0, stream>>>(uv, trigW, trigb, slab, out);

    // rs+re heads: single 4-batch pass if the workspace can hold the full L
    // buffer (4 x 16384 x 256 floats over the R overlay), else 2x2-batch.
    size_t need4 = (off + (size_t)4 * 16384 * 256) * sizeof(float);
    if (ws_size >= need4) {
        k_logits2<<<dim3(128, 4), 256, 0, stream>>>(uv, rsW, rsb, reW, reb, Lbuf);
        k_loss2<<<16384, 256, 0, stream>>>(Lbuf, slab, elab,
                                           out + 1, out + 1 + 65536, out);
    } else {
        for (int bp = 0; bp < 2; bp++) {
            k_logits2<<<dim3(128, 2), 256, 0, stream>>>(uv + (size_t)bp * 2 * 128 * 1600,
                                                        rsW, rsb, reW, reb, Lbuf);
            k_loss2<<<8192, 256, 0, stream>>>(Lbuf,
                                              slab + (size_t)bp * 2 * 16384, elab + (size_t)bp * 2 * 16384,
                                              out + 1 + (size_t)bp * 2 * 16384,
                                              out + 1 + 65536 + (size_t)bp * 2 * 16384, out);
        }
    }
}

// Round 9
// 2041.036 us; speedup vs baseline: 1.3708x; 1.3708x over previous
//
#include <hip/hip_runtime.h>
#include <hip/hip_bf16.h>

// Problem dims
#define B4 4
#define S128 128
#define T129 129
#define H800 800
#define E256 256
#define NE 66
#define NR 122
#define DPW 8      // LSTM dims per WG
#define NWGD 100   // LSTM WGs per direction

typedef float f32x4 __attribute__((ext_vector_type(4)));

#define HB_ROW 900

// ---------------------------------------------------------------------------
__device__ __forceinline__ float gelu_f(float x) {
    float t = 0.7978845608028654f * (x + 0.044715f * x * x * x);
    float e = __expf(2.f * t);
    float th = 1.f - 2.f / (e + 1.f);
    return 0.5f * x * (1.f + th);
}

// embed(m, c): element of the concatenated input x[516][800], built on the fly
__device__ __forceinline__ float embed_at(const float* __restrict__ bert,
                                          const int* __restrict__ pids,
                                          const float* __restrict__ ptab,
                                          int m, int c)
{
    if (c < 768) return bert[(size_t)m * 768 + c];
    int t = m % T129, b = m / T129;
    if (t == 0) return 0.f;
    return ptab[pids[b * S128 + t - 1] * 32 + (c - 768)];
}

// ---------------------------------------------------------------------------
// Generic fp32 tiled GEMM with register-prefetch pipeline (R5-proven T14).
// AMODE 1: xg-view row. BTRANS 1: A@B^T.
template<int AMODE, int BTRANS, int EPI>
__global__ __launch_bounds__(256) void k_gemm(const float* __restrict__ A, const float* __restrict__ Bm,
                                              const float* __restrict__ bias, const float* __restrict__ res,
                                              float* __restrict__ C, int M, int N, int K)
{
    __shared__ float As[16][68];
    __shared__ float Bs[16][68];
    int m0 = blockIdx.x * 64, n0 = blockIdx.y * 64;
    int tid = threadIdx.x;
    int tm = tid & 15, tn = tid >> 4;
    int kkA = tid & 15, mmb = tid >> 4;       // A-stage coords (also BTRANS=1 B-stage)
    int nnB = (tid & 15) * 4, kkB = tid >> 4; // B-stage coords (BTRANS=0)
    float acc[4][4] = {};
    float aP[4], bP[4];

    // prefetch chunk k0 = 0
    #pragma unroll
    for (int q = 0; q < 4; q++) {
        int m = m0 + mmb + q * 16;
        float v = 0.f;
        if (m < M) {
            int row = (AMODE == 1) ? (m + (m >> 7) + 1) : m;
            v = A[(size_t)row * K + kkA];
        }
        aP[q] = v;
    }
    if (BTRANS == 0) {
        int n = n0 + nnB;
        if (n + 3 < N) {
            float4 bv = *(const float4*)&Bm[(size_t)kkB * N + n];
            bP[0] = bv.x; bP[1] = bv.y; bP[2] = bv.z; bP[3] = bv.w;
        } else {
            #pragma unroll
            for (int q = 0; q < 4; q++)
                bP[q] = (n + q < N) ? Bm[(size_t)kkB * N + n + q] : 0.f;
        }
    } else {
        #pragma unroll
        for (int q = 0; q < 4; q++) {
            int n = n0 + mmb + q * 16;
            bP[q] = (n < N) ? Bm[(size_t)n * K + kkA] : 0.f;
        }
    }

    for (int k0 = 0; k0 < K; k0 += 16) {
        float aC[4], bC[4];
        #pragma unroll
        for (int q = 0; q < 4; q++) { aC[q] = aP[q]; bC[q] = bP[q]; }

        // issue next chunk's loads (clamped; results unused on last iter)
        int kn = (k0 + 16 < K) ? (k0 + 16) : 0;
        #pragma unroll
        for (int q = 0; q < 4; q++) {
            int m = m0 + mmb + q * 16;
            float v = 0.f;
            if (m < M) {
                int row = (AMODE == 1) ? (m + (m >> 7) + 1) : m;
                v = A[(size_t)row * K + kn + kkA];
            }
            aP[q] = v;
        }
        if (BTRANS == 0) {
            int n = n0 + nnB;
            if (n + 3 < N) {
                float4 bv = *(const float4*)&Bm[(size_t)(kn + kkB) * N + n];
                bP[0] = bv.x; bP[1] = bv.y; bP[2] = bv.z; bP[3] = bv.w;
            } else {
                #pragma unroll
                for (int q = 0; q < 4; q++)
                    bP[q] = (n + q < N) ? Bm[(size_t)(kn + kkB) * N + n + q] : 0.f;
            }
        } else {
            #pragma unroll
            for (int q = 0; q < 4; q++) {
                int n = n0 + mmb + q * 16;
                bP[q] = (n < N) ? Bm[(size_t)n * K + kn + kkA] : 0.f;
            }
        }

        // stage current chunk from registers
        #pragma unroll
        for (int q = 0; q < 4; q++)
            As[kkA][mmb + q * 16] = aC[q];
        if (BTRANS == 0) {
            Bs[kkB][nnB + 0] = bC[0]; Bs[kkB][nnB + 1] = bC[1];
            Bs[kkB][nnB + 2] = bC[2]; Bs[kkB][nnB + 3] = bC[3];
        } else {
            #pragma unroll
            for (int q = 0; q < 4; q++)
                Bs[kkA][mmb + q * 16] = bC[q];
        }
        __syncthreads();
        #pragma unroll
        for (int kk = 0; kk < 16; kk++) {
            float4 a = *(const float4*)&As[kk][tm * 4];
            float4 bb = *(const float4*)&Bs[kk][tn * 4];
            float av[4] = {a.x, a.y, a.z, a.w};
            float bv[4] = {bb.x, bb.y, bb.z, bb.w};
            #pragma unroll
            for (int xx = 0; xx < 4; xx++)
                #pragma unroll
                for (int yy = 0; yy < 4; yy++)
                    acc[xx][yy] += av[xx] * bv[yy];
        }
        __syncthreads();
    }
    #pragma unroll
    for (int xx = 0; xx < 4; xx++) {
        int m = m0 + tm * 4 + xx;
        if (m >= M) continue;
        #pragma unroll
        for (int yy = 0; yy < 4; yy++) {
            int n = n0 + tn * 4 + yy;
            if (n >= N) continue;
            float v = acc[xx][yy];
            if (bias) v += bias[n];
            if (EPI == 1) v = res[(size_t)m * N + n] + fmaxf(v, 0.f);
            C[(size_t)m * N + n] = v;
        }
    }
}

// ---------------------------------------------------------------------------
// Merged Wih GEMM with FUSED EMBED A-tile + register-prefetch pipeline:
// C[516][6400] = embed(x) @ [Wih_f | Wih_b]^T + [bl_f | bl_b].
__global__ __launch_bounds__(256) void k_gemm_wih(const float* __restrict__ bert,
                                                  const int* __restrict__ pids,
                                                  const float* __restrict__ ptab,
                                                  const float* __restrict__ Wf, const float* __restrict__ Wb,
                                                  const float* __restrict__ bf, const float* __restrict__ bb_,
                                                  float* __restrict__ C)
{
    __shared__ float As[16][68];
    __shared__ float Bs[16][68];
    const int M = 516, K = 800, N = 6400;
    int m0 = blockIdx.x * 64, n0 = blockIdx.y * 64;
    const float* W  = (n0 < 3200) ? Wf : Wb;
    const float* bi = (n0 < 3200) ? bf : bb_;
    int nb = (n0 < 3200) ? n0 : (n0 - 3200);
    int tid = threadIdx.x;
    int tm = tid & 15, tn = tid >> 4;
    int kk_s = tid & 15, mmb = tid >> 4;
    int mrow[4]; int pofs[4]; bool mok[4];
    #pragma unroll
    for (int q = 0; q < 4; q++) {
        int m = m0 + mmb + q * 16;
        mrow[q] = m;
        mok[q] = m < M;
        int t = m % T129, b = m / T129;
        pofs[q] = (mok[q] && t > 0) ? pids[b * S128 + t - 1] * 32 : -1;
    }
    float acc[4][4] = {};
    float aP[4], bP[4];

    // prefetch chunk k0 = 0
    #pragma unroll
    for (int q = 0; q < 4; q++) {
        float v = 0.f;
        if (mok[q]) {
            if (kk_s < 768) v = bert[(size_t)mrow[q] * 768 + kk_s];
            else            v = (pofs[q] < 0) ? 0.f : ptab[pofs[q] + kk_s - 768];
        }
        aP[q] = v;
    }
    #pragma unroll
    for (int q = 0; q < 4; q++)
        bP[q] = W[(size_t)(nb + mmb + q * 16) * K + kk_s];

    for (int k0 = 0; k0 < K; k0 += 16) {
        float aC[4], bC[4];
        #pragma unroll
        for (int q = 0; q < 4; q++) { aC[q] = aP[q]; bC[q] = bP[q]; }

        int kn = (k0 + 16 < K) ? (k0 + 16) : 0;
        {
            int c = kn + kk_s;
            #pragma unroll
            for (int q = 0; q < 4; q++) {
                float v = 0.f;
                if (mok[q]) {
                    if (c < 768) v = bert[(size_t)mrow[q] * 768 + c];
                    else         v = (pofs[q] < 0) ? 0.f : ptab[pofs[q] + c - 768];
                }
                aP[q] = v;
            }
        }
        #pragma unroll
        for (int q = 0; q < 4; q++)
            bP[q] = W[(size_t)(nb + mmb + q * 16) * K + kn + kk_s];

        #pragma unroll
        for (int q = 0; q < 4; q++)
            As[kk_s][mmb + q * 16] = aC[q];
        #pragma unroll
        for (int q = 0; q < 4; q++)
            Bs[kk_s][mmb + q * 16] = bC[q];
        __syncthreads();
        #pragma unroll
        for (int kk = 0; kk < 16; kk++) {
            float4 a = *(const float4*)&As[kk][tm * 4];
            float4 bb = *(const float4*)&Bs[kk][tn * 4];
            float av[4] = {a.x, a.y, a.z, a.w};
            float bv[4] = {bb.x, bb.y, bb.z, bb.w};
            #pragma unroll
            for (int xx = 0; xx < 4; xx++)
                #pragma unroll
                for (int yy = 0; yy < 4; yy++)
                    acc[xx][yy] += av[xx] * bv[yy];
        }
        __syncthreads();
    }
    #pragma unroll
    for (int xx = 0; xx < 4; xx++) {
        int m = m0 + tm * 4 + xx;
        if (m >= M) continue;
        #pragma unroll
        for (int yy = 0; yy < 4; yy++) {
            int n = n0 + tn * 4 + yy;
            C[(size_t)m * N + n] = acc[xx][yy] + bi[nb + (n - n0)];
        }
    }
}

// ---------------------------------------------------------------------------
// fc GEMM with FUSED EMBED residual + register-prefetch pipeline:
// xg = embed(x) + relu(lstm @ fcW + fcb).
__global__ __launch_bounds__(256) void k_gemm_fc(const float* __restrict__ A, const float* __restrict__ Bm,
                                                 const float* __restrict__ bias,
                                                 const float* __restrict__ bert, const int* __restrict__ pids,
                                                 const float* __restrict__ ptab, float* __restrict__ C)
{
    __shared__ float As[16][68];
    __shared__ float Bs[16][68];
    const int M = 516, N = 800, K = 1600;
    int m0 = blockIdx.x * 64, n0 = blockIdx.y * 64;
    int tid = threadIdx.x;
    int tm = tid & 15, tn = tid >> 4;
    int kkA = tid & 15, mmb = tid >> 4;
    int nnB = (tid & 15) * 4, kkB = tid >> 4;
    float acc[4][4] = {};
    float aP[4], bP[4];

    // prefetch chunk k0 = 0
    #pragma unroll
    for (int q = 0; q < 4; q++) {
        int m = m0 + mmb + q * 16;
        aP[q] = (m < M) ? A[(size_t)m * K + kkA] : 0.f;
    }
    {
        int n = n0 + nnB;
        if (n + 3 < N) {
            float4 bv = *(const float4*)&Bm[(size_t)kkB * N + n];
            bP[0] = bv.x; bP[1] = bv.y; bP[2] = bv.z; bP[3] = bv.w;
        } else {
            #pragma unroll
            for (int q = 0; q < 4; q++)
                bP[q] = (n + q < N) ? Bm[(size_t)kkB * N + n + q] : 0.f;
        }
    }

    for (int k0 = 0; k0 < K; k0 += 16) {
        float aC[4], bC[4];
        #pragma unroll
        for (int q = 0; q < 4; q++) { aC[q] = aP[q]; bC[q] = bP[q]; }

        int kn = (k0 + 16 < K) ? (k0 + 16) : 0;
        #pragma unroll
        for (int q = 0; q < 4; q++) {
            int m = m0 + mmb + q * 16;
            aP[q] = (m < M) ? A[(size_t)m * K + kn + kkA] : 0.f;
        }
        {
            int n = n0 + nnB;
            if (n + 3 < N) {
                float4 bv = *(const float4*)&Bm[(size_t)(kn + kkB) * N + n];
                bP[0] = bv.x; bP[1] = bv.y; bP[2] = bv.z; bP[3] = bv.w;
            } else {
                #pragma unroll
                for (int q = 0; q < 4; q++)
                    bP[q] = (n + q < N) ? Bm[(size_t)(kn + kkB) * N + n + q] : 0.f;
            }
        }

        #pragma unroll
        for (int q = 0; q < 4; q++)
            As[kkA][mmb + q * 16] = aC[q];
        Bs[kkB][nnB + 0] = bC[0]; Bs[kkB][nnB + 1] = bC[1];
        Bs[kkB][nnB + 2] = bC[2]; Bs[kkB][nnB + 3] = bC[3];
        __syncthreads();
        #pragma unroll
        for (int kk = 0; kk < 16; kk++) {
            float4 a = *(const float4*)&As[kk][tm * 4];
            float4 bb = *(const float4*)&Bs[kk][tn * 4];
            float av[4] = {a.x, a.y, a.z, a.w};
            float bv[4] = {bb.x, bb.y, bb.z, bb.w};
            #pragma unroll
            for (int xx = 0; xx < 4; xx++)
                #pragma unroll
                for (int yy = 0; yy < 4; yy++)
                    acc[xx][yy] += av[xx] * bv[yy];
        }
        __syncthreads();
    }
    #pragma unroll
    for (int xx = 0; xx < 4; xx++) {
        int m = m0 + tm * 4 + xx;
        if (m >= M) continue;
        #pragma unroll
        for (int yy = 0; yy < 4; yy++) {
            int n = n0 + tn * 4 + yy;
            if (n >= N) continue;
            float v = fmaxf(acc[xx][yy] + bias[n], 0.f);
            C[(size_t)m * N + n] = embed_at(bert, pids, ptab, m, n) + v;
        }
    }
}

// ---------------------------------------------------------------------------
// Merged table GEMM + register-prefetch pipeline:
// uv[512][1600]; col n<800: g2@tW[:800] + tb; else g2@tW[800:].
__global__ __launch_bounds__(256) void k_gemm_uv(const float* __restrict__ A, const float* __restrict__ tW,
                                                 const float* __restrict__ tb, float* __restrict__ C)
{
    __shared__ float As[16][68];
    __shared__ float Bs[16][68];
    const int M = 512, K = 800, N = 1600;
    int m0 = blockIdx.x * 64, n0 = blockIdx.y * 64;
    int tid = threadIdx.x;
    int tm = tid & 15, tn = tid >> 4;
    int kkA = tid & 15, mmb = tid >> 4;
    int nnB = (tid & 15) * 4, kkB = tid >> 4;
    float acc[4][4] = {};
    float aP[4], bP[4];

    // prefetch chunk k0 = 0
    #pragma unroll
    for (int q = 0; q < 4; q++)
        aP[q] = A[(size_t)(m0 + mmb + q * 16) * K + kkA];
    #pragma unroll
    for (int q = 0; q < 4; q++) {
        int n = n0 + nnB + q;
        bP[q] = (n < 800) ? tW[(size_t)kkB * 800 + n]
                          : tW[(size_t)(800 + kkB) * 800 + (n - 800)];
    }

    for (int k0 = 0; k0 < K; k0 += 16) {
        float aC[4], bC[4];
        #pragma unroll
        for (int q = 0; q < 4; q++) { aC[q] = aP[q]; bC[q] = bP[q]; }

        int kn = (k0 + 16 < K) ? (k0 + 16) : 0;
        #pragma unroll
        for (int q = 0; q < 4; q++)
            aP[q] = A[(size_t)(m0 + mmb + q * 16) * K + kn + kkA];
        #pragma unroll
        for (int q = 0; q < 4; q++) {
            int n = n0 + nnB + q;
            bP[q] = (n < 800) ? tW[(size_t)(kn + kkB) * 800 + n]
                              : tW[(size_t)(800 + kn + kkB) * 800 + (n - 800)];
        }

        #pragma unroll
        for (int q = 0; q < 4; q++)
            As[kkA][mmb + q * 16] = aC[q];
        #pragma unroll
        for (int q = 0; q < 4; q++)
            Bs[kkB][nnB + q] = bC[q];
        __syncthreads();
        #pragma unroll
        for (int kk = 0; kk < 16; kk++) {
            float4 a = *(const float4*)&As[kk][tm * 4];
            float4 bb = *(const float4*)&Bs[kk][tn * 4];
            float av[4] = {a.x, a.y, a.z, a.w};
            float bv[4] = {bb.x, bb.y, bb.z, bb.w};
            #pragma unroll
            for (int xx = 0; xx < 4; xx++)
                #pragma unroll
                for (int yy = 0; yy < 4; yy++)
                    acc[xx][yy] += av[xx] * bv[yy];
        }
        __syncthreads();
    }
    #pragma unroll
    for (int xx = 0; xx < 4; xx++) {
        int m = m0 + tm * 4 + xx;
        #pragma unroll
        for (int yy = 0; yy < 4; yy++) {
            int n = n0 + tn * 4 + yy;
            float v = acc[xx][yy];
            if (n < 800) v += tb[n];
            C[(size_t)m * N + n] = v;
        }
    }
}

// ---------------------------------------------------------------------------
// Persistent BiLSTM v11 (BEST-KNOWN, reverted from v12):
//  - hpk pre-filled with 0x7F bytes (float 3.39e38 sentinel) each launch.
//  - LSTM h in (-1,1): a granule whose 4 floats are all |v| < 1.5 is real
//    data. Each 16B granule is one lane's single global_store_dwordx4
//    (committed as a unit) -> no torn-granule hazard.
//  - consumers poll the DATA granules directly: the poll load IS the data
//    load (no flag hop, no detect->load serialization).
//  - v12's light-detect and merged wave0 reduce both REGRESSED (r3:
//    +50us, 4x LDS bank conflicts) -> reverted.
__global__ __launch_bounds__(256) void k_lstm(const float* __restrict__ xW,
                                              const float* __restrict__ Whhf, const float* __restrict__ Whhb,
                                              float* __restrict__ lstm, float* __restrict__ hpk)
{
    __shared__ float hb[4][HB_ROW];     // staggered h_{t-1}
    __shared__ float gsum[25][32][4];   // [slice][g*8+d][b]
    __shared__ float gg[128];           // reduced gates: idx (g<<5)|(d<<2)|b
    int wg = blockIdx.x;
    int dir = wg >= NWGD ? 1 : 0;
    int wgd = dir ? wg - NWGD : wg;
    const float* Whh = dir ? Whhb : Whhf;
    const float* xWd = xW + dir * 3200;
    int tid = threadIdx.x;
    bool dotth = tid < 200;
    int d = tid & 7, sl = tid >> 3;     // valid for dotth (sl 0..24)
    int k0 = sl * 32;
    int rb = tid & 3, rd = (tid >> 2) & 7, rg = tid >> 5;
    int lane = tid & 63;

    float wreg[4][32];
    if (dotth) {
        #pragma unroll
        for (int g = 0; g < 4; g++) {
            const float* wp = Whh + (size_t)(g * 800 + wgd * DPW + d) * 800 + k0;
            #pragma unroll
            for (int q = 0; q < 32; q += 4)
                *(float4*)&wreg[g][q] = *(const float4*)&wp[q];
        }
    }
    for (int i = tid; i < 4 * HB_ROW; i += 256) (&hb[0][0])[i] = 0.f;
    __syncthreads();

    float cst = 0.f;                    // cell state (tid<32)

    for (int step = 0; step < 129; step++) {
        int t = dir ? (128 - step) : step;
        float xq = 0.f;
        if (tid < 128)
            xq = xWd[(size_t)(rb * T129 + t) * 6400 + rg * 800 + wgd * DPW + rd];
        if (step > 0) {
            int tprev = dir ? (t + 1) : (t - 1);
            if (tid < 200) {
                const f32x4* pb = (const f32x4*)(hpk + (size_t)(dir * 129 + tprev) * 3200);
                const f32x4* p0 = pb + tid;
                const f32x4* p1 = pb + tid + 200;
                const f32x4* p2 = pb + tid + 400;
                const f32x4* p3 = pb + tid + 600;
                f32x4 v0, v1, v2, v3;
                long long iters = 0;
                for (;;) {
                    asm volatile(
                        "global_load_dwordx4 %0, %4, off sc0 sc1\n\t"
                        "global_load_dwordx4 %1, %5, off sc0 sc1\n\t"
                        "global_load_dwordx4 %2, %6, off sc0 sc1\n\t"
                        "global_load_dwordx4 %3, %7, off sc0 sc1\n\t"
                        "s_waitcnt vmcnt(0)"
                        : "=&v"(v0), "=&v"(v1), "=&v"(v2), "=&v"(v3)
                        : "v"(p0), "v"(p1), "v"(p2), "v"(p3)
                        : "memory");
                    bool ok = fabsf(v0.x) < 1.5f && fabsf(v0.y) < 1.5f &&
                              fabsf(v0.z) < 1.5f && fabsf(v0.w) < 1.5f &&
                              fabsf(v1.x) < 1.5f && fabsf(v1.y) < 1.5f &&
                              fabsf(v1.z) < 1.5f && fabsf(v1.w) < 1.5f &&
                              fabsf(v2.x) < 1.5f && fabsf(v2.y) < 1.5f &&
                              fabsf(v2.z) < 1.5f && fabsf(v2.w) < 1.5f &&
                              fabsf(v3.x) < 1.5f && fabsf(v3.y) < 1.5f &&
                              fabsf(v3.z) < 1.5f && fabsf(v3.w) < 1.5f;
                    if (ok) break;
                    if (++iters > 20000000LL) break;
                }
                // packed slot s (f32x4 index in [0,800)):
                //   wg = s>>3, b = (s&7)>>1, d0 = (s&1)*4, dim p = wg*8+d0
                //   staggered hb slot = b*225 + (p>>5)*9 + ((p&31)>>2)
                {
                    int s0 = tid;
                    int p_ = (s0 >> 3) * 8 + (s0 & 1) * 4;
                    ((f32x4*)&hb[0][0])[((s0 & 7) >> 1) * 225 + (p_ >> 5) * 9 + ((p_ & 31) >> 2)] = v0;
                }
                {
                    int s1 = tid + 200;
                    int p_ = (s1 >> 3) * 8 + (s1 & 1) * 4;
                    ((f32x4*)&hb[0][0])[((s1 & 7) >> 1) * 225 + (p_ >> 5) * 9 + ((p_ & 31) >> 2)] = v1;
                }
                {
                    int s2 = tid + 400;
                    int p_ = (s2 >> 3) * 8 + (s2 & 1) * 4;
                    ((f32x4*)&hb[0][0])[((s2 & 7) >> 1) * 225 + (p_ >> 5) * 9 + ((p_ & 31) >> 2)] = v2;
                }
                {
                    int s3 = tid + 600;
                    int p_ = (s3 >> 3) * 8 + (s3 & 1) * 4;
                    ((f32x4*)&hb[0][0])[((s3 & 7) >> 1) * 225 + (p_ >> 5) * 9 + ((p_ & 31) >> 2)] = v3;
                }
            }
            __syncthreads();
        }
        if (dotth) {
            float a[4][4] = {};   // [gate][batch]
            #pragma unroll
            for (int b = 0; b < 4; b++) {
                const float* hrow = &hb[b][0];
                #pragma unroll
                for (int q = 0; q < 32; q += 4) {
                    float4 h = *(const float4*)&hrow[sl * 36 + q];
                    #pragma unroll
                    for (int g = 0; g < 4; g++)
                        a[g][b] += wreg[g][q] * h.x + wreg[g][q + 1] * h.y
                                 + wreg[g][q + 2] * h.z + wreg[g][q + 3] * h.w;
                }
            }
            #pragma unroll
            for (int g = 0; g < 4; g++)
                *(float4*)&gsum[sl][g * 8 + d][0] = make_float4(a[g][0], a[g][1], a[g][2], a[g][3]);
        }
        __syncthreads();
        if (tid < 128) {
            float s = xq;
            #pragma unroll
            for (int ss = 0; ss < 25; ss++) s += gsum[ss][rg * 8 + rd][rb];
            gg[tid] = s;
        }
        __syncthreads();
        float hv = 0.f;
        if (tid < 32) {
            int dd = tid & 7, bb2 = tid >> 3;
            float gi = gg[(0 << 5) | (dd << 2) | bb2];
            float gf = gg[(1 << 5) | (dd << 2) | bb2];
            float gG = gg[(2 << 5) | (dd << 2) | bb2];
            float go = gg[(3 << 5) | (dd << 2) | bb2];
            float si = 1.f / (1.f + __expf(-gi));
            float sf = 1.f / (1.f + __expf(-gf));
            float so = 1.f / (1.f + __expf(-go));
            cst = sf * cst + si * tanhf(gG);
            hv = so * tanhf(cst);
        }
        if (tid < 64) {
            int src = (lane & 7) * 4;
            f32x4 o;
            o.x = __shfl(hv, src + 0, 64);
            o.y = __shfl(hv, src + 1, 64);
            o.z = __shfl(hv, src + 2, 64);
            o.w = __shfl(hv, src + 3, 64);
            // packed publish: lane l -> r = 4*l .. 4*l+3 of this WG's 32-float line.
            // No vmcnt, no flag: validity is in-band (|h| < 1).
            if (lane < 8) {
                float* pp = hpk + ((size_t)(dir * 129 + t) * 100 + wgd) * 32 + lane * 4;
                asm volatile("global_store_dwordx4 %0, %1, off sc0 sc1"
                             :: "v"((f32x4*)pp), "v"(o) : "memory");
            }
            // standard-layout store for k_gemm_fc (post-kernel consumer):
            // off the critical path, fire-and-forget.
            if (lane < 8) {
                int bb = lane >> 1, half = lane & 1;
                float* ap = lstm + (size_t)((bb * T129 + t) * 1600) + dir * 800 + wgd * DPW + half * 4;
                asm volatile("global_store_dwordx4 %0, %1, off sc0 sc1"
                             :: "v"((f32x4*)ap), "v"(o) : "memory");
            }
        }
    }
}

// ---------------------------------------------------------------------------
// Fused GAT layer (coef + softmax + aggregate), one block per (b,h).
template<int RESMODE>
__global__ __launch_bounds__(512) void k_gat_fused(const int* __restrict__ esrc, const int* __restrict__ edst,
                                                   const float* __restrict__ h1,
                                                   const float* __restrict__ asrc, const float* __restrict__ adst,
                                                   const float* __restrict__ gbias,
                                                   const float* __restrict__ res, float* __restrict__ out)
{
    __shared__ int se[384], de[384];
    __shared__ float asl[128], adl[128], ml[128], dl_[128];
    int bh = blockIdx.x;
    int b = bh >> 3, h = bh & 7;
    int t = threadIdx.x;
    if (t < 384) {
        if (t < E256) { se[t] = esrc[b * E256 + t]; de[t] = edst[b * E256 + t]; }
        else          { se[t] = t - E256;           de[t] = t - E256; }
    }
    int node = t >> 2, ch = t & 3;
    int dd0 = ch * 25;
    {
        const float* hp = h1 + (size_t)(b * S128 + node) * H800 + h * 100 + dd0;
        const float* ap = asrc + h * 100 + dd0;
        const float* dp = adst + h * 100 + dd0;
        float s1 = 0.f, s2 = 0.f;
        #pragma unroll
        for (int q = 0; q < 25; q++) { float hv = hp[q]; s1 += hv * ap[q]; s2 += hv * dp[q]; }
        s1 += __shfl_xor(s1, 1, 64); s1 += __shfl_xor(s1, 2, 64);
        s2 += __shfl_xor(s2, 1, 64); s2 += __shfl_xor(s2, 2, 64);
        if (ch == 0) { asl[node] = s1; adl[node] = s2; }
    }
    __syncthreads();
    if (t < 128) {
        float myad = adl[t];
        float m = -3.4e38f;
        for (int e = 0; e < 384; e++)
            if (de[e] == t) {
                float sc = asl[se[e]] + myad;
                sc = (sc > 0.f) ? sc : 0.2f * sc;
                m = fmaxf(m, sc);
            }
        float den = 0.f;
        for (int e = 0; e < 384; e++)
            if (de[e] == t) {
                float sc = asl[se[e]] + myad;
                sc = (sc > 0.f) ? sc : 0.2f * sc;
                den += __expf(sc - m);
            }
        ml[t] = m; dl_[t] = den;
    }
    __syncthreads();
    float acc[25] = {};
    float myad = adl[node], mym = ml[node];
    for (int e = 0; e < 384; e++) {
        if (de[e] == node) {
            int s = se[e];
            float sc = asl[s] + myad;
            sc = (sc > 0.f) ? sc : 0.2f * sc;
            float w = __expf(sc - mym);
            const float* hp = h1 + (size_t)(b * S128 + s) * H800 + h * 100 + dd0;
            #pragma unroll
            for (int q = 0; q < 25; q++) acc[q] += w * hp[q];
        }
    }
    float inv = 1.f / dl_[node];
    int n = b * S128 + node;
    size_t rrow = (RESMODE == 1) ? (size_t)(n + b + 1) * H800 : (size_t)n * H800;
    #pragma unroll
    for (int q = 0; q < 25; q++) {
        int col = h * 100 + dd0 + q;
        float v = acc[q] * inv + gbias[col];
        out[(size_t)n * H800 + col] = res[rrow + col] + fmaxf(v, 0.f);
    }
}

// ---------------------------------------------------------------------------
// Trig head, diagonal only. uv stride 1600: u = row, v = row+800.
__global__ __launch_bounds__(64) void k_trig(const float* __restrict__ uv,
                                             const float* __restrict__ W, const float* __restrict__ bias,
                                             const int* __restrict__ labels, float* __restrict__ d_out)
{
    __shared__ float s[800];
    __shared__ float lg[66];
    int bi = blockIdx.x;          // b*128+i
    int i = bi & 127;
    int l = threadIdx.x;
    const float* ur = uv + (size_t)bi * 1600;
    const float* vr = ur + 800;
    for (int k = l; k < 800; k += 64) s[k] = gelu_f(ur[k] + vr[k]);
    __syncthreads();
    float a0 = 0.f, a1 = 0.f;
    bool has2 = (l < 2);
    for (int k = 0; k < 800; k++) {
        float sv = s[k];
        a0 += sv * W[k * NE + l];
        if (has2) a1 += sv * W[k * NE + 64 + l];
    }
    lg[l] = a0 + bias[l];
    if (has2) lg[64 + l] = a1 + bias[64 + l];
    __syncthreads();
    if (l == 0) {
        float m = lg[0];
        for (int c = 1; c < NE; c++) m = fmaxf(m, lg[c]);
        float se = 0.f, sl = 0.f, bv = lg[0];
        int am = 0;
        for (int c = 0; c < NE; c++) {
            se += __expf(lg[c] - m);
            sl += lg[c];
            if (lg[c] > bv) { bv = lg[c]; am = c; }
        }
        float lse = m + __logf(se);
        int tgt = labels[(size_t)bi * S128 + i];
        float ce = (0.1f / NE) * (NE * lse - sl) + 0.9f * (lse - lg[tgt]);
        atomicAdd(d_out, ce * (1.f / 128.f));
        int r = bi * S128 + i;
        d_out[1 + r] = (float)am;
        d_out[1 + 65536 + r] = (float)am;
    }
}

// ---------------------------------------------------------------------------
// Fused rs+re logits, NB batches per launch (blockIdx.y). uv stride 1600.
// v5 = v4 (128x256 tile, 8x16/thread; numerics VERIFIED in R8) with the two
// R8 defects fixed:
//  (1) __launch_bounds__(256) -- no min-occupancy arg. R8's (256,2) clamped
//      VGPR to 128 < the 128-reg accumulator -> scratch spill (FETCH_SIZE
//      10.9MB -> 726MB). Peak live regs ~190 < 256 default cap.
//  (2) As row stride 196 (196%32=4), was 192 (multiple of 32 banks -> the
//      16 kk-rows aliased onto identical banks: 16-way write conflict,
//      SQ_LDS_BANK_CONFLICT 25M). Write banks now (4*kk + word)%32 = each
//      bank exactly 2 lanes (free, m136); read bases tm*12%32 = 8 banks x
//      2-way (free). Swizzle word = r + 4*(r>>3) retained.
__global__ __launch_bounds__(256) void k_logits2(const float* __restrict__ uvb,
                                                 const float* __restrict__ rsW, const float* __restrict__ rsb,
                                                 const float* __restrict__ reW, const float* __restrict__ reb,
                                                 float* __restrict__ L)
{
    __shared__ float As[2][16][196];    // swizzled row word: r + ((r>>3)<<2), max 187
    __shared__ float Bs[4][16][68];     // per-wave col slice
    int bi = blockIdx.y;
    const float* base = uvb + (size_t)bi * 128 * 1600;
    float* Lb = L + (size_t)bi * 16384 * 256;
    int il = blockIdx.x;
    const float* urow = base + (size_t)il * 1600;
    int tid = threadIdx.x;
    int wv = tid >> 6, lane = tid & 63;
    int tm = tid & 15, tn = tid >> 4;       // rows tm*8..+7, cols tn*16..+15
    int cln = (lane >> 4) * 16;             // within-wave col offset
    float acc[8][16] = {};
    int hc = (tid < 128) ? tid : (tid - 128);
    const float* Wp = (tid < 128) ? rsW : reW;
    bool cok = hc < NR;
    int kk = tid & 15, rrb = tid >> 4;      // staging: k=kk, rows rrb+q*16

    // --- prologue ---
    float u0 = urow[kk];
    float v0q[8];
    #pragma unroll
    for (int q = 0; q < 8; q++)
        v0q[q] = base[(size_t)(rrb + q * 16) * 1600 + 800 + kk];
    float wP[16];
    #pragma unroll
    for (int kk2 = 0; kk2 < 16; kk2++)
        wP[kk2] = cok ? Wp[(size_t)kk2 * NR + hc] : 0.f;
    float uP = urow[16 + kk];
    float vP[8];
    #pragma unroll
    for (int q = 0; q < 8; q++)
        vP[q] = base[(size_t)(rrb + q * 16) * 1600 + 800 + 16 + kk];

    // stage As[0] (chunk 0)
    #pragma unroll
    for (int q = 0; q < 8; q++) {
        int r = rrb + q * 16;
        As[0][kk][r + ((r >> 3) << 2)] = gelu_f(u0 + v0q[q]);
    }
    __syncthreads();

    for (int c = 0; c < 50; ++c) {
        // stage Bs (chunk c) -- wave-private, no barrier needed
        #pragma unroll
        for (int kk2 = 0; kk2 < 16; kk2++)
            Bs[wv][kk2][lane] = wP[kk2];
        // stage As[(c+1)&1] (chunk c+1)
        #pragma unroll
        for (int q = 0; q < 8; q++) {
            int r = rrb + q * 16;
            As[(c + 1) & 1][kk][r + ((r >> 3) << 2)] = gelu_f(uP + vP[q]);
        }
        // prefetch: W <- chunk c+1, u/v <- chunk c+2 (clamped)
        int k1 = (c + 1 < 50) ? (c + 1) * 16 : 0;
        int k2 = (c + 2 < 50) ? (c + 2) * 16 : 0;
        #pragma unroll
        for (int kk2 = 0; kk2 < 16; kk2++)
            wP[kk2] = cok ? Wp[(size_t)(k1 + kk2) * NR + hc] : 0.f;
        uP = urow[k2 + kk];
        #pragma unroll
        for (int q = 0; q < 8; q++)
            vP[q] = base[(size_t)(rrb + q * 16) * 1600 + 800 + k2 + kk];

        // compute chunk c from As[c&1] + this wave's Bs slice
        const float (*Ac)[196] = As[c & 1];
        #pragma unroll
        for (int kki = 0; kki < 16; kki++) {
            float4 a0 = *(const float4*)&Ac[kki][tm * 12];
            float4 a1 = *(const float4*)&Ac[kki][tm * 12 + 4];
            float4 b0 = *(const float4*)&Bs[wv][kki][cln];
            float4 b1 = *(const float4*)&Bs[wv][kki][cln + 4];
            float4 b2 = *(const float4*)&Bs[wv][kki][cln + 8];
            float4 b3 = *(const float4*)&Bs[wv][kki][cln + 12];
            float av[8]  = {a0.x, a0.y, a0.z, a0.w, a1.x, a1.y, a1.z, a1.w};
            float bvv[16] = {b0.x, b0.y, b0.z, b0.w, b1.x, b1.y, b1.z, b1.w,
                             b2.x, b2.y, b2.z, b2.w, b3.x, b3.y, b3.z, b3.w};
            #pragma unroll
            for (int xx = 0; xx < 8; xx++)
                #pragma unroll
                for (int yy = 0; yy < 16; yy++)
                    acc[xx][yy] += av[xx] * bvv[yy];
        }
        __syncthreads();
    }
    // epilogue: rows il*128 + tm*8+xx, cols tn*16+yy (all 16 same head)
    const float* bp = (tn >= 8) ? reb : rsb;
    #pragma unroll
    for (int xx = 0; xx < 8; xx++) {
        int r = il * S128 + tm * 8 + xx;
        float* Lr = Lb + (size_t)r * 256 + tn * 16;
        #pragma unroll
        for (int hf = 0; hf < 4; hf++) {
            int cb = (tn * 16 + hf * 4) & 127;
            if (cb + 3 < NR) {
                float4 o = make_float4(acc[xx][hf*4+0] + bp[cb+0], acc[xx][hf*4+1] + bp[cb+1],
                                       acc[xx][hf*4+2] + bp[cb+2], acc[xx][hf*4+3] + bp[cb+3]);
                *(float4*)(Lr + hf * 4) = o;
            } else {
                #pragma unroll
                for (int q = 0; q < 4; q++)
                    if (cb + q < NR) Lr[hf * 4 + q] = acc[xx][hf*4+q] + bp[cb+q];
            }
        }
    }
}

// CE loss + symmetric argmax, both heads. Handles any number of batches via
// grid size: rr in [0, nbatch*16384), bi = rr>>14 indexes L/labels/results.
__global__ __launch_bounds__(256) void k_loss2(const float* __restrict__ L,
                                               const int* __restrict__ lab0, const int* __restrict__ lab1,
                                               float* __restrict__ res0, float* __restrict__ res1,
                                               float* __restrict__ lossptr)
{
    __shared__ float wsum[4];
    int wv = threadIdx.x >> 6, l = threadIdx.x & 63;
    int rr = blockIdx.x * 4 + wv;
    int bi = rr >> 14;
    int r = rr & 16383;
    int i = r >> 7, j = r & 127;
    size_t bioff = (size_t)bi * 16384;
    float ces = 0.f;
    if (i != j) {
        const float* row  = L + (bioff + r) * 256;
        const float* prow = L + (bioff + ((j << 7) | i)) * 256;
        bool v2 = (l < NR - 64);
        #pragma unroll
        for (int hd = 0; hd < 2; hd++) {
            const float* rw = row + hd * 128;
            const float* pw = prow + hd * 128;
            float x1 = rw[l];
            float x2 = v2 ? rw[l + 64] : -3.4e38f;
            float m = fmaxf(x1, x2);
            #pragma unroll
            for (int s = 32; s; s >>= 1) m = fmaxf(m, __shfl_xor(m, s, 64));
            float se = __expf(x1 - m) + (v2 ? __expf(x2 - m) : 0.f);
            float sl = x1 + (v2 ? x2 : 0.f);
            #pragma unroll
            for (int s = 32; s; s >>= 1) { se += __shfl_xor(se, s, 64); sl += __shfl_xor(sl, s, 64); }
            float lse = m + __logf(se);
            int tgt = (hd ? lab1 : lab0)[bioff + r];
            float lt = rw[tgt];
            ces += (0.1f / NR) * (NR * lse - sl) + 0.9f * (lse - lt);
            float y1 = x1 + pw[l];
            float y2 = v2 ? (x2 + pw[l + 64]) : -3.4e38f;
            float bv; int bidx;
            if (y2 > y1) { bv = y2; bidx = l + 64; } else { bv = y1; bidx = l; }
            #pragma unroll
            for (int s = 32; s; s >>= 1) {
                float ov = __shfl_xor(bv, s, 64);
                int oi = __shfl_xor(bidx, s, 64);
                if (ov > bv || (ov == bv && oi < bidx)) { bv = ov; bidx = oi; }
            }
            if (l == 0) (hd ? res1 : res0)[bioff + r] = (float)bidx;
        }
    }
    if (l == 0) wsum[wv] = ces;
    __syncthreads();
    if (threadIdx.x == 0) {
        float s = (wsum[0] + wsum[1] + wsum[2] + wsum[3]) * (1.f / 16256.f);
        atomicAdd(lossptr, s);
    }
}

// ---------------------------------------------------------------------------
extern "C" void kernel_launch(void* const* d_in, const int* in_sizes, int n_in,
                              void* d_out, int out_size, void* d_ws, size_t ws_size,
                              hipStream_t stream)
{
    (void)in_sizes; (void)n_in; (void)out_size;
    const float* bert  = (const float*)d_in[0];
    const int*   pids  = (const int*)d_in[1];
    const int*   esrc  = (const int*)d_in[2];
    const int*   edst  = (const int*)d_in[3];
    const int*   slab  = (const int*)d_in[4];
    const int*   elab  = (const int*)d_in[5];
    const float* ptab  = (const float*)d_in[6];
    const float* Wih_f = (const float*)d_in[7];
    const float* Whh_f = (const float*)d_in[8];
    const float* bl_f  = (const float*)d_in[9];
    const float* Wih_b = (const float*)d_in[10];
    const float* Whh_b = (const float*)d_in[11];
    const float* bl_b  = (const float*)d_in[12];
    const float* fcW   = (const float*)d_in[13];
    const float* fcb   = (const float*)d_in[14];
    const float* tW    = (const float*)d_in[15];
    const float* tb    = (const float*)d_in[16];
    const float* gatW  = (const float*)d_in[17];
    const float* asrc  = (const float*)d_in[18];
    const float* adst  = (const float*)d_in[19];
    const float* gbias = (const float*)d_in[20];
    const float* trigW = (const float*)d_in[21];
    const float* trigb = (const float*)d_in[22];
    const float* rsW   = (const float*)d_in[23];
    const float* rsb   = (const float*)d_in[24];
    const float* reW   = (const float*)d_in[25];
    const float* reb   = (const float*)d_in[26];
    float* out = (float*)d_out;

    float* ws = (float*)d_ws;
    size_t off = 0;
    auto alloc = [&](size_t n) { float* p = ws + off; off += (n + 255) & ~(size_t)255; return p; };
    float* uv    = alloc((size_t)512 * 1600);     // live late (trig/logits)
    float* R     = ws + off;                      // overlay region
    size_t roff = 0;
    auto ralloc = [&](size_t n) { float* p = R + roff; roff += (n + 255) & ~(size_t)255; return p; };
    float* xW   = ralloc((size_t)516 * 6400);
    float* lstm = ralloc((size_t)516 * 1600);
    float* xg   = ralloc(516 * 800);
    float* h1   = ralloc(512 * 800);
    float* g1   = ralloc(512 * 800);
    float* g2   = ralloc(512 * 800);
    float* hpk  = ralloc((size_t)2 * 129 * 100 * 32);  // packed h exchange; dead before Lbuf
    float* Lbuf = R;   // overlays dead temps

    hipMemsetAsync(d_out, 0, 4, stream);                 // loss accumulator
    // sentinel-fill the h exchange: 0x7F7F7F7F = 3.39e38 (|v| >= 1.5 => not yet written).
    // Stream-ordered before k_lstm, so workspace poison can never look valid.
    hipMemsetAsync(hpk, 0x7F, (size_t)2 * 129 * 100 * 32 * sizeof(float), stream);

    // merged gate-input precompute with fused embed
    k_gemm_wih<<<dim3(9, 100), 256, 0, stream>>>(bert, pids, ptab, Wih_f, Wih_b, bl_f, bl_b, xW);

    k_lstm<<<2 * NWGD, 256, 0, stream>>>(xW, Whh_f, Whh_b, lstm, hpk);

    // xg = embed(x) + relu(lstm @ fcW + fcb)
    k_gemm_fc<<<dim3(9, 13), 256, 0, stream>>>(lstm, fcW, fcb, bert, pids, ptab, xg);

    // GAT layer 1 (input = xg[:,1:,:] view)
    k_gemm<1, 0, 0><<<dim3(8, 13), 256, 0, stream>>>(xg, gatW, nullptr, nullptr, h1, 512, 800, 800);
    k_gat_fused<1><<<32, 512, 0, stream>>>(esrc, edst, h1, asrc, adst, gbias, xg, g1);
    // GAT layer 2
    k_gemm<0, 0, 0><<<dim3(8, 13), 256, 0, stream>>>(g1, gatW, nullptr, nullptr, h1, 512, 800, 800);
    k_gat_fused<0><<<32, 512, 0, stream>>>(esrc, edst, h1, asrc, adst, gbias, g1, g2);

    // merged table split: uv[512][1600] (u | v)
    k_gemm_uv<<<dim3(8, 25), 256, 0, stream>>>(g2, tW, tb, uv);

    // trig head (diag)
    k_trig<<<512, 64, 0, stream>>>(uv, trigW, trigb, slab, out);

    // rs+re heads: single 4-batch pass if the workspace can hold the full L
    // buffer (4 x 16384 x 256 floats over the R overlay), else 2x2-batch.
    size_t need4 = (off + (size_t)4 * 16384 * 256) * sizeof(float);
    if (ws_size >= need4) {
        k_logits2<<<dim3(128, 4), 256, 0, stream>>>(uv, rsW, rsb, reW, reb, Lbuf);
        k_loss2<<<16384, 256, 0, stream>>>(Lbuf, slab, elab,
                                           out + 1, out + 1 + 65536, out);
    } else {
        for (int bp = 0; bp < 2; bp++) {
            k_logits2<<<dim3(128, 2), 256, 0, stream>>>(uv + (size_t)bp * 2 * 128 * 1600,
                                                        rsW, rsb, reW, reb, Lbuf);
            k_loss2<<<8192, 256, 0, stream>>>(Lbuf,
                                              slab + (size_t)bp * 2 * 16384, elab + (size_t)bp * 2 * 16384,
                                              out + 1 + (size_t)bp * 2 * 16384,
                                              out + 1 + 65536 + (size_t)bp * 2 * 16384, out);
        }
    }
}

// Round 10
// 1907.836 us; speedup vs baseline: 1.4665x; 1.0698x over previous
//
#include <hip/hip_runtime.h>
#include <hip/hip_bf16.h>

// Problem dims
#define B4 4
#define S128 128
#define T129 129
#define H800 800
#define E256 256
#define NE 66
#define NR 122
#define DPW 8      // LSTM dims per WG
#define NWGD 100   // LSTM WGs per direction

typedef float f32x4 __attribute__((ext_vector_type(4)));

#define HB_ROW 900

// ---------------------------------------------------------------------------
__device__ __forceinline__ float gelu_f(float x) {
    float t = 0.7978845608028654f * (x + 0.044715f * x * x * x);
    float e = __expf(2.f * t);
    float th = 1.f - 2.f / (e + 1.f);
    return 0.5f * x * (1.f + th);
}

// embed(m, c): element of the concatenated input x[516][800], built on the fly
__device__ __forceinline__ float embed_at(const float* __restrict__ bert,
                                          const int* __restrict__ pids,
                                          const float* __restrict__ ptab,
                                          int m, int c)
{
    if (c < 768) return bert[(size_t)m * 768 + c];
    int t = m % T129, b = m / T129;
    if (t == 0) return 0.f;
    return ptab[pids[b * S128 + t - 1] * 32 + (c - 768)];
}

// ---------------------------------------------------------------------------
// Generic fp32 tiled GEMM with register-prefetch pipeline (R5-proven T14).
// AMODE 1: xg-view row. BTRANS 1: A@B^T.
template<int AMODE, int BTRANS, int EPI>
__global__ __launch_bounds__(256) void k_gemm(const float* __restrict__ A, const float* __restrict__ Bm,
                                              const float* __restrict__ bias, const float* __restrict__ res,
                                              float* __restrict__ C, int M, int N, int K)
{
    __shared__ float As[16][68];
    __shared__ float Bs[16][68];
    int m0 = blockIdx.x * 64, n0 = blockIdx.y * 64;
    int tid = threadIdx.x;
    int tm = tid & 15, tn = tid >> 4;
    int kkA = tid & 15, mmb = tid >> 4;       // A-stage coords (also BTRANS=1 B-stage)
    int nnB = (tid & 15) * 4, kkB = tid >> 4; // B-stage coords (BTRANS=0)
    float acc[4][4] = {};
    float aP[4], bP[4];

    // prefetch chunk k0 = 0
    #pragma unroll
    for (int q = 0; q < 4; q++) {
        int m = m0 + mmb + q * 16;
        float v = 0.f;
        if (m < M) {
            int row = (AMODE == 1) ? (m + (m >> 7) + 1) : m;
            v = A[(size_t)row * K + kkA];
        }
        aP[q] = v;
    }
    if (BTRANS == 0) {
        int n = n0 + nnB;
        if (n + 3 < N) {
            float4 bv = *(const float4*)&Bm[(size_t)kkB * N + n];
            bP[0] = bv.x; bP[1] = bv.y; bP[2] = bv.z; bP[3] = bv.w;
        } else {
            #pragma unroll
            for (int q = 0; q < 4; q++)
                bP[q] = (n + q < N) ? Bm[(size_t)kkB * N + n + q] : 0.f;
        }
    } else {
        #pragma unroll
        for (int q = 0; q < 4; q++) {
            int n = n0 + mmb + q * 16;
            bP[q] = (n < N) ? Bm[(size_t)n * K + kkA] : 0.f;
        }
    }

    for (int k0 = 0; k0 < K; k0 += 16) {
        float aC[4], bC[4];
        #pragma unroll
        for (int q = 0; q < 4; q++) { aC[q] = aP[q]; bC[q] = bP[q]; }

        // issue next chunk's loads (clamped; results unused on last iter)
        int kn = (k0 + 16 < K) ? (k0 + 16) : 0;
        #pragma unroll
        for (int q = 0; q < 4; q++) {
            int m = m0 + mmb + q * 16;
            float v = 0.f;
            if (m < M) {
                int row = (AMODE == 1) ? (m + (m >> 7) + 1) : m;
                v = A[(size_t)row * K + kn + kkA];
            }
            aP[q] = v;
        }
        if (BTRANS == 0) {
            int n = n0 + nnB;
            if (n + 3 < N) {
                float4 bv = *(const float4*)&Bm[(size_t)(kn + kkB) * N + n];
                bP[0] = bv.x; bP[1] = bv.y; bP[2] = bv.z; bP[3] = bv.w;
            } else {
                #pragma unroll
                for (int q = 0; q < 4; q++)
                    bP[q] = (n + q < N) ? Bm[(size_t)(kn + kkB) * N + n + q] : 0.f;
            }
        } else {
            #pragma unroll
            for (int q = 0; q < 4; q++) {
                int n = n0 + mmb + q * 16;
                bP[q] = (n < N) ? Bm[(size_t)n * K + kn + kkA] : 0.f;
            }
        }

        // stage current chunk from registers
        #pragma unroll
        for (int q = 0; q < 4; q++)
            As[kkA][mmb + q * 16] = aC[q];
        if (BTRANS == 0) {
            Bs[kkB][nnB + 0] = bC[0]; Bs[kkB][nnB + 1] = bC[1];
            Bs[kkB][nnB + 2] = bC[2]; Bs[kkB][nnB + 3] = bC[3];
        } else {
            #pragma unroll
            for (int q = 0; q < 4; q++)
                Bs[kkA][mmb + q * 16] = bC[q];
        }
        __syncthreads();
        #pragma unroll
        for (int kk = 0; kk < 16; kk++) {
            float4 a = *(const float4*)&As[kk][tm * 4];
            float4 bb = *(const float4*)&Bs[kk][tn * 4];
            float av[4] = {a.x, a.y, a.z, a.w};
            float bv[4] = {bb.x, bb.y, bb.z, bb.w};
            #pragma unroll
            for (int xx = 0; xx < 4; xx++)
                #pragma unroll
                for (int yy = 0; yy < 4; yy++)
                    acc[xx][yy] += av[xx] * bv[yy];
        }
        __syncthreads();
    }
    #pragma unroll
    for (int xx = 0; xx < 4; xx++) {
        int m = m0 + tm * 4 + xx;
        if (m >= M) continue;
        #pragma unroll
        for (int yy = 0; yy < 4; yy++) {
            int n = n0 + tn * 4 + yy;
            if (n >= N) continue;
            float v = acc[xx][yy];
            if (bias) v += bias[n];
            if (EPI == 1) v = res[(size_t)m * N + n] + fmaxf(v, 0.f);
            C[(size_t)m * N + n] = v;
        }
    }
}

// ---------------------------------------------------------------------------
// Merged Wih GEMM with FUSED EMBED A-tile + register-prefetch pipeline:
// C[516][6400] = embed(x) @ [Wih_f | Wih_b]^T + [bl_f | bl_b].
__global__ __launch_bounds__(256) void k_gemm_wih(const float* __restrict__ bert,
                                                  const int* __restrict__ pids,
                                                  const float* __restrict__ ptab,
                                                  const float* __restrict__ Wf, const float* __restrict__ Wb,
                                                  const float* __restrict__ bf, const float* __restrict__ bb_,
                                                  float* __restrict__ C)
{
    __shared__ float As[16][68];
    __shared__ float Bs[16][68];
    const int M = 516, K = 800, N = 6400;
    int m0 = blockIdx.x * 64, n0 = blockIdx.y * 64;
    const float* W  = (n0 < 3200) ? Wf : Wb;
    const float* bi = (n0 < 3200) ? bf : bb_;
    int nb = (n0 < 3200) ? n0 : (n0 - 3200);
    int tid = threadIdx.x;
    int tm = tid & 15, tn = tid >> 4;
    int kk_s = tid & 15, mmb = tid >> 4;
    int mrow[4]; int pofs[4]; bool mok[4];
    #pragma unroll
    for (int q = 0; q < 4; q++) {
        int m = m0 + mmb + q * 16;
        mrow[q] = m;
        mok[q] = m < M;
        int t = m % T129, b = m / T129;
        pofs[q] = (mok[q] && t > 0) ? pids[b * S128 + t - 1] * 32 : -1;
    }
    float acc[4][4] = {};
    float aP[4], bP[4];

    // prefetch chunk k0 = 0
    #pragma unroll
    for (int q = 0; q < 4; q++) {
        float v = 0.f;
        if (mok[q]) {
            if (kk_s < 768) v = bert[(size_t)mrow[q] * 768 + kk_s];
            else            v = (pofs[q] < 0) ? 0.f : ptab[pofs[q] + kk_s - 768];
        }
        aP[q] = v;
    }
    #pragma unroll
    for (int q = 0; q < 4; q++)
        bP[q] = W[(size_t)(nb + mmb + q * 16) * K + kk_s];

    for (int k0 = 0; k0 < K; k0 += 16) {
        float aC[4], bC[4];
        #pragma unroll
        for (int q = 0; q < 4; q++) { aC[q] = aP[q]; bC[q] = bP[q]; }

        int kn = (k0 + 16 < K) ? (k0 + 16) : 0;
        {
            int c = kn + kk_s;
            #pragma unroll
            for (int q = 0; q < 4; q++) {
                float v = 0.f;
                if (mok[q]) {
                    if (c < 768) v = bert[(size_t)mrow[q] * 768 + c];
                    else         v = (pofs[q] < 0) ? 0.f : ptab[pofs[q] + c - 768];
                }
                aP[q] = v;
            }
        }
        #pragma unroll
        for (int q = 0; q < 4; q++)
            bP[q] = W[(size_t)(nb + mmb + q * 16) * K + kn + kk_s];

        #pragma unroll
        for (int q = 0; q < 4; q++)
            As[kk_s][mmb + q * 16] = aC[q];
        #pragma unroll
        for (int q = 0; q < 4; q++)
            Bs[kk_s][mmb + q * 16] = bC[q];
        __syncthreads();
        #pragma unroll
        for (int kk = 0; kk < 16; kk++) {
            float4 a = *(const float4*)&As[kk][tm * 4];
            float4 bb = *(const float4*)&Bs[kk][tn * 4];
            float av[4] = {a.x, a.y, a.z, a.w};
            float bv[4] = {bb.x, bb.y, bb.z, bb.w};
            #pragma unroll
            for (int xx = 0; xx < 4; xx++)
                #pragma unroll
                for (int yy = 0; yy < 4; yy++)
                    acc[xx][yy] += av[xx] * bv[yy];
        }
        __syncthreads();
    }
    #pragma unroll
    for (int xx = 0; xx < 4; xx++) {
        int m = m0 + tm * 4 + xx;
        if (m >= M) continue;
        #pragma unroll
        for (int yy = 0; yy < 4; yy++) {
            int n = n0 + tn * 4 + yy;
            C[(size_t)m * N + n] = acc[xx][yy] + bi[nb + (n - n0)];
        }
    }
}

// ---------------------------------------------------------------------------
// fc GEMM with FUSED EMBED residual + register-prefetch pipeline:
// xg = embed(x) + relu(lstm @ fcW + fcb).
__global__ __launch_bounds__(256) void k_gemm_fc(const float* __restrict__ A, const float* __restrict__ Bm,
                                                 const float* __restrict__ bias,
                                                 const float* __restrict__ bert, const int* __restrict__ pids,
                                                 const float* __restrict__ ptab, float* __restrict__ C)
{
    __shared__ float As[16][68];
    __shared__ float Bs[16][68];
    const int M = 516, N = 800, K = 1600;
    int m0 = blockIdx.x * 64, n0 = blockIdx.y * 64;
    int tid = threadIdx.x;
    int tm = tid & 15, tn = tid >> 4;
    int kkA = tid & 15, mmb = tid >> 4;
    int nnB = (tid & 15) * 4, kkB = tid >> 4;
    float acc[4][4] = {};
    float aP[4], bP[4];

    // prefetch chunk k0 = 0
    #pragma unroll
    for (int q = 0; q < 4; q++) {
        int m = m0 + mmb + q * 16;
        aP[q] = (m < M) ? A[(size_t)m * K + kkA] : 0.f;
    }
    {
        int n = n0 + nnB;
        if (n + 3 < N) {
            float4 bv = *(const float4*)&Bm[(size_t)kkB * N + n];
            bP[0] = bv.x; bP[1] = bv.y; bP[2] = bv.z; bP[3] = bv.w;
        } else {
            #pragma unroll
            for (int q = 0; q < 4; q++)
                bP[q] = (n + q < N) ? Bm[(size_t)kkB * N + n + q] : 0.f;
        }
    }

    for (int k0 = 0; k0 < K; k0 += 16) {
        float aC[4], bC[4];
        #pragma unroll
        for (int q = 0; q < 4; q++) { aC[q] = aP[q]; bC[q] = bP[q]; }

        int kn = (k0 + 16 < K) ? (k0 + 16) : 0;
        #pragma unroll
        for (int q = 0; q < 4; q++) {
            int m = m0 + mmb + q * 16;
            aP[q] = (m < M) ? A[(size_t)m * K + kn + kkA] : 0.f;
        }
        {
            int n = n0 + nnB;
            if (n + 3 < N) {
                float4 bv = *(const float4*)&Bm[(size_t)(kn + kkB) * N + n];
                bP[0] = bv.x; bP[1] = bv.y; bP[2] = bv.z; bP[3] = bv.w;
            } else {
                #pragma unroll
                for (int q = 0; q < 4; q++)
                    bP[q] = (n + q < N) ? Bm[(size_t)(kn + kkB) * N + n + q] : 0.f;
            }
        }

        #pragma unroll
        for (int q = 0; q < 4; q++)
            As[kkA][mmb + q * 16] = aC[q];
        Bs[kkB][nnB + 0] = bC[0]; Bs[kkB][nnB + 1] = bC[1];
        Bs[kkB][nnB + 2] = bC[2]; Bs[kkB][nnB + 3] = bC[3];
        __syncthreads();
        #pragma unroll
        for (int kk = 0; kk < 16; kk++) {
            float4 a = *(const float4*)&As[kk][tm * 4];
            float4 bb = *(const float4*)&Bs[kk][tn * 4];
            float av[4] = {a.x, a.y, a.z, a.w};
            float bv[4] = {bb.x, bb.y, bb.z, bb.w};
            #pragma unroll
            for (int xx = 0; xx < 4; xx++)
                #pragma unroll
                for (int yy = 0; yy < 4; yy++)
                    acc[xx][yy] += av[xx] * bv[yy];
        }
        __syncthreads();
    }
    #pragma unroll
    for (int xx = 0; xx < 4; xx++) {
        int m = m0 + tm * 4 + xx;
        if (m >= M) continue;
        #pragma unroll
        for (int yy = 0; yy < 4; yy++) {
            int n = n0 + tn * 4 + yy;
            if (n >= N) continue;
            float v = fmaxf(acc[xx][yy] + bias[n], 0.f);
            C[(size_t)m * N + n] = embed_at(bert, pids, ptab, m, n) + v;
        }
    }
}

// ---------------------------------------------------------------------------
// Merged table GEMM + register-prefetch pipeline:
// uv[512][1600]; col n<800: g2@tW[:800] + tb; else g2@tW[800:].
__global__ __launch_bounds__(256) void k_gemm_uv(const float* __restrict__ A, const float* __restrict__ tW,
                                                 const float* __restrict__ tb, float* __restrict__ C)
{
    __shared__ float As[16][68];
    __shared__ float Bs[16][68];
    const int M = 512, K = 800, N = 1600;
    int m0 = blockIdx.x * 64, n0 = blockIdx.y * 64;
    int tid = threadIdx.x;
    int tm = tid & 15, tn = tid >> 4;
    int kkA = tid & 15, mmb = tid >> 4;
    int nnB = (tid & 15) * 4, kkB = tid >> 4;
    float acc[4][4] = {};
    float aP[4], bP[4];

    // prefetch chunk k0 = 0
    #pragma unroll
    for (int q = 0; q < 4; q++)
        aP[q] = A[(size_t)(m0 + mmb + q * 16) * K + kkA];
    #pragma unroll
    for (int q = 0; q < 4; q++) {
        int n = n0 + nnB + q;
        bP[q] = (n < 800) ? tW[(size_t)kkB * 800 + n]
                          : tW[(size_t)(800 + kkB) * 800 + (n - 800)];
    }

    for (int k0 = 0; k0 < K; k0 += 16) {
        float aC[4], bC[4];
        #pragma unroll
        for (int q = 0; q < 4; q++) { aC[q] = aP[q]; bC[q] = bP[q]; }

        int kn = (k0 + 16 < K) ? (k0 + 16) : 0;
        #pragma unroll
        for (int q = 0; q < 4; q++)
            aP[q] = A[(size_t)(m0 + mmb + q * 16) * K + kn + kkA];
        #pragma unroll
        for (int q = 0; q < 4; q++) {
            int n = n0 + nnB + q;
            bP[q] = (n < 800) ? tW[(size_t)(kn + kkB) * 800 + n]
                              : tW[(size_t)(800 + kn + kkB) * 800 + (n - 800)];
        }

        #pragma unroll
        for (int q = 0; q < 4; q++)
            As[kkA][mmb + q * 16] = aC[q];
        #pragma unroll
        for (int q = 0; q < 4; q++)
            Bs[kkB][nnB + q] = bC[q];
        __syncthreads();
        #pragma unroll
        for (int kk = 0; kk < 16; kk++) {
            float4 a = *(const float4*)&As[kk][tm * 4];
            float4 bb = *(const float4*)&Bs[kk][tn * 4];
            float av[4] = {a.x, a.y, a.z, a.w};
            float bv[4] = {bb.x, bb.y, bb.z, bb.w};
            #pragma unroll
            for (int xx = 0; xx < 4; xx++)
                #pragma unroll
                for (int yy = 0; yy < 4; yy++)
                    acc[xx][yy] += av[xx] * bv[yy];
        }
        __syncthreads();
    }
    #pragma unroll
    for (int xx = 0; xx < 4; xx++) {
        int m = m0 + tm * 4 + xx;
        #pragma unroll
        for (int yy = 0; yy < 4; yy++) {
            int n = n0 + tn * 4 + yy;
            float v = acc[xx][yy];
            if (n < 800) v += tb[n];
            C[(size_t)m * N + n] = v;
        }
    }
}

// ---------------------------------------------------------------------------
// Persistent BiLSTM v11 (BEST-KNOWN, reverted from v12):
//  - hpk pre-filled with 0x7F bytes (float 3.39e38 sentinel) each launch.
//  - LSTM h in (-1,1): a granule whose 4 floats are all |v| < 1.5 is real
//    data. Each 16B granule is one lane's single global_store_dwordx4
//    (committed as a unit) -> no torn-granule hazard.
//  - consumers poll the DATA granules directly: the poll load IS the data
//    load (no flag hop, no detect->load serialization).
//  - v12's light-detect and merged wave0 reduce both REGRESSED (r3:
//    +50us, 4x LDS bank conflicts) -> reverted.
__global__ __launch_bounds__(256) void k_lstm(const float* __restrict__ xW,
                                              const float* __restrict__ Whhf, const float* __restrict__ Whhb,
                                              float* __restrict__ lstm, float* __restrict__ hpk)
{
    __shared__ float hb[4][HB_ROW];     // staggered h_{t-1}
    __shared__ float gsum[25][32][4];   // [slice][g*8+d][b]
    __shared__ float gg[128];           // reduced gates: idx (g<<5)|(d<<2)|b
    int wg = blockIdx.x;
    int dir = wg >= NWGD ? 1 : 0;
    int wgd = dir ? wg - NWGD : wg;
    const float* Whh = dir ? Whhb : Whhf;
    const float* xWd = xW + dir * 3200;
    int tid = threadIdx.x;
    bool dotth = tid < 200;
    int d = tid & 7, sl = tid >> 3;     // valid for dotth (sl 0..24)
    int k0 = sl * 32;
    int rb = tid & 3, rd = (tid >> 2) & 7, rg = tid >> 5;
    int lane = tid & 63;

    float wreg[4][32];
    if (dotth) {
        #pragma unroll
        for (int g = 0; g < 4; g++) {
            const float* wp = Whh + (size_t)(g * 800 + wgd * DPW + d) * 800 + k0;
            #pragma unroll
            for (int q = 0; q < 32; q += 4)
                *(float4*)&wreg[g][q] = *(const float4*)&wp[q];
        }
    }
    for (int i = tid; i < 4 * HB_ROW; i += 256) (&hb[0][0])[i] = 0.f;
    __syncthreads();

    float cst = 0.f;                    // cell state (tid<32)

    for (int step = 0; step < 129; step++) {
        int t = dir ? (128 - step) : step;
        float xq = 0.f;
        if (tid < 128)
            xq = xWd[(size_t)(rb * T129 + t) * 6400 + rg * 800 + wgd * DPW + rd];
        if (step > 0) {
            int tprev = dir ? (t + 1) : (t - 1);
            if (tid < 200) {
                const f32x4* pb = (const f32x4*)(hpk + (size_t)(dir * 129 + tprev) * 3200);
                const f32x4* p0 = pb + tid;
                const f32x4* p1 = pb + tid + 200;
                const f32x4* p2 = pb + tid + 400;
                const f32x4* p3 = pb + tid + 600;
                f32x4 v0, v1, v2, v3;
                long long iters = 0;
                for (;;) {
                    asm volatile(
                        "global_load_dwordx4 %0, %4, off sc0 sc1\n\t"
                        "global_load_dwordx4 %1, %5, off sc0 sc1\n\t"
                        "global_load_dwordx4 %2, %6, off sc0 sc1\n\t"
                        "global_load_dwordx4 %3, %7, off sc0 sc1\n\t"
                        "s_waitcnt vmcnt(0)"
                        : "=&v"(v0), "=&v"(v1), "=&v"(v2), "=&v"(v3)
                        : "v"(p0), "v"(p1), "v"(p2), "v"(p3)
                        : "memory");
                    bool ok = fabsf(v0.x) < 1.5f && fabsf(v0.y) < 1.5f &&
                              fabsf(v0.z) < 1.5f && fabsf(v0.w) < 1.5f &&
                              fabsf(v1.x) < 1.5f && fabsf(v1.y) < 1.5f &&
                              fabsf(v1.z) < 1.5f && fabsf(v1.w) < 1.5f &&
                              fabsf(v2.x) < 1.5f && fabsf(v2.y) < 1.5f &&
                              fabsf(v2.z) < 1.5f && fabsf(v2.w) < 1.5f &&
                              fabsf(v3.x) < 1.5f && fabsf(v3.y) < 1.5f &&
                              fabsf(v3.z) < 1.5f && fabsf(v3.w) < 1.5f;
                    if (ok) break;
                    if (++iters > 20000000LL) break;
                }
                // packed slot s (f32x4 index in [0,800)):
                //   wg = s>>3, b = (s&7)>>1, d0 = (s&1)*4, dim p = wg*8+d0
                //   staggered hb slot = b*225 + (p>>5)*9 + ((p&31)>>2)
                {
                    int s0 = tid;
                    int p_ = (s0 >> 3) * 8 + (s0 & 1) * 4;
                    ((f32x4*)&hb[0][0])[((s0 & 7) >> 1) * 225 + (p_ >> 5) * 9 + ((p_ & 31) >> 2)] = v0;
                }
                {
                    int s1 = tid + 200;
                    int p_ = (s1 >> 3) * 8 + (s1 & 1) * 4;
                    ((f32x4*)&hb[0][0])[((s1 & 7) >> 1) * 225 + (p_ >> 5) * 9 + ((p_ & 31) >> 2)] = v1;
                }
                {
                    int s2 = tid + 400;
                    int p_ = (s2 >> 3) * 8 + (s2 & 1) * 4;
                    ((f32x4*)&hb[0][0])[((s2 & 7) >> 1) * 225 + (p_ >> 5) * 9 + ((p_ & 31) >> 2)] = v2;
                }
                {
                    int s3 = tid + 600;
                    int p_ = (s3 >> 3) * 8 + (s3 & 1) * 4;
                    ((f32x4*)&hb[0][0])[((s3 & 7) >> 1) * 225 + (p_ >> 5) * 9 + ((p_ & 31) >> 2)] = v3;
                }
            }
            __syncthreads();
        }
        if (dotth) {
            float a[4][4] = {};   // [gate][batch]
            #pragma unroll
            for (int b = 0; b < 4; b++) {
                const float* hrow = &hb[b][0];
                #pragma unroll
                for (int q = 0; q < 32; q += 4) {
                    float4 h = *(const float4*)&hrow[sl * 36 + q];
                    #pragma unroll
                    for (int g = 0; g < 4; g++)
                        a[g][b] += wreg[g][q] * h.x + wreg[g][q + 1] * h.y
                                 + wreg[g][q + 2] * h.z + wreg[g][q + 3] * h.w;
                }
            }
            #pragma unroll
            for (int g = 0; g < 4; g++)
                *(float4*)&gsum[sl][g * 8 + d][0] = make_float4(a[g][0], a[g][1], a[g][2], a[g][3]);
        }
        __syncthreads();
        if (tid < 128) {
            float s = xq;
            #pragma unroll
            for (int ss = 0; ss < 25; ss++) s += gsum[ss][rg * 8 + rd][rb];
            gg[tid] = s;
        }
        __syncthreads();
        float hv = 0.f;
        if (tid < 32) {
            int dd = tid & 7, bb2 = tid >> 3;
            float gi = gg[(0 << 5) | (dd << 2) | bb2];
            float gf = gg[(1 << 5) | (dd << 2) | bb2];
            float gG = gg[(2 << 5) | (dd << 2) | bb2];
            float go = gg[(3 << 5) | (dd << 2) | bb2];
            float si = 1.f / (1.f + __expf(-gi));
            float sf = 1.f / (1.f + __expf(-gf));
            float so = 1.f / (1.f + __expf(-go));
            cst = sf * cst + si * tanhf(gG);
            hv = so * tanhf(cst);
        }
        if (tid < 64) {
            int src = (lane & 7) * 4;
            f32x4 o;
            o.x = __shfl(hv, src + 0, 64);
            o.y = __shfl(hv, src + 1, 64);
            o.z = __shfl(hv, src + 2, 64);
            o.w = __shfl(hv, src + 3, 64);
            // packed publish: lane l -> r = 4*l .. 4*l+3 of this WG's 32-float line.
            // No vmcnt, no flag: validity is in-band (|h| < 1).
            if (lane < 8) {
                float* pp = hpk + ((size_t)(dir * 129 + t) * 100 + wgd) * 32 + lane * 4;
                asm volatile("global_store_dwordx4 %0, %1, off sc0 sc1"
                             :: "v"((f32x4*)pp), "v"(o) : "memory");
            }
            // standard-layout store for k_gemm_fc (post-kernel consumer):
            // off the critical path, fire-and-forget.
            if (lane < 8) {
                int bb = lane >> 1, half = lane & 1;
                float* ap = lstm + (size_t)((bb * T129 + t) * 1600) + dir * 800 + wgd * DPW + half * 4;
                asm volatile("global_store_dwordx4 %0, %1, off sc0 sc1"
                             :: "v"((f32x4*)ap), "v"(o) : "memory");
            }
        }
    }
}

// ---------------------------------------------------------------------------
// Fused GAT layer (coef + softmax + aggregate), one block per (b,h).
template<int RESMODE>
__global__ __launch_bounds__(512) void k_gat_fused(const int* __restrict__ esrc, const int* __restrict__ edst,
                                                   const float* __restrict__ h1,
                                                   const float* __restrict__ asrc, const float* __restrict__ adst,
                                                   const float* __restrict__ gbias,
                                                   const float* __restrict__ res, float* __restrict__ out)
{
    __shared__ int se[384], de[384];
    __shared__ float asl[128], adl[128], ml[128], dl_[128];
    int bh = blockIdx.x;
    int b = bh >> 3, h = bh & 7;
    int t = threadIdx.x;
    if (t < 384) {
        if (t < E256) { se[t] = esrc[b * E256 + t]; de[t] = edst[b * E256 + t]; }
        else          { se[t] = t - E256;           de[t] = t - E256; }
    }
    int node = t >> 2, ch = t & 3;
    int dd0 = ch * 25;
    {
        const float* hp = h1 + (size_t)(b * S128 + node) * H800 + h * 100 + dd0;
        const float* ap = asrc + h * 100 + dd0;
        const float* dp = adst + h * 100 + dd0;
        float s1 = 0.f, s2 = 0.f;
        #pragma unroll
        for (int q = 0; q < 25; q++) { float hv = hp[q]; s1 += hv * ap[q]; s2 += hv * dp[q]; }
        s1 += __shfl_xor(s1, 1, 64); s1 += __shfl_xor(s1, 2, 64);
        s2 += __shfl_xor(s2, 1, 64); s2 += __shfl_xor(s2, 2, 64);
        if (ch == 0) { asl[node] = s1; adl[node] = s2; }
    }
    __syncthreads();
    if (t < 128) {
        float myad = adl[t];
        float m = -3.4e38f;
        for (int e = 0; e < 384; e++)
            if (de[e] == t) {
                float sc = asl[se[e]] + myad;
                sc = (sc > 0.f) ? sc : 0.2f * sc;
                m = fmaxf(m, sc);
            }
        float den = 0.f;
        for (int e = 0; e < 384; e++)
            if (de[e] == t) {
                float sc = asl[se[e]] + myad;
                sc = (sc > 0.f) ? sc : 0.2f * sc;
                den += __expf(sc - m);
            }
        ml[t] = m; dl_[t] = den;
    }
    __syncthreads();
    float acc[25] = {};
    float myad = adl[node], mym = ml[node];
    for (int e = 0; e < 384; e++) {
        if (de[e] == node) {
            int s = se[e];
            float sc = asl[s] + myad;
            sc = (sc > 0.f) ? sc : 0.2f * sc;
            float w = __expf(sc - mym);
            const float* hp = h1 + (size_t)(b * S128 + s) * H800 + h * 100 + dd0;
            #pragma unroll
            for (int q = 0; q < 25; q++) acc[q] += w * hp[q];
        }
    }
    float inv = 1.f / dl_[node];
    int n = b * S128 + node;
    size_t rrow = (RESMODE == 1) ? (size_t)(n + b + 1) * H800 : (size_t)n * H800;
    #pragma unroll
    for (int q = 0; q < 25; q++) {
        int col = h * 100 + dd0 + q;
        float v = acc[q] * inv + gbias[col];
        out[(size_t)n * H800 + col] = res[rrow + col] + fmaxf(v, 0.f);
    }
}

// ---------------------------------------------------------------------------
// Trig head, diagonal only. uv stride 1600: u = row, v = row+800.
__global__ __launch_bounds__(64) void k_trig(const float* __restrict__ uv,
                                             const float* __restrict__ W, const float* __restrict__ bias,
                                             const int* __restrict__ labels, float* __restrict__ d_out)
{
    __shared__ float s[800];
    __shared__ float lg[66];
    int bi = blockIdx.x;          // b*128+i
    int i = bi & 127;
    int l = threadIdx.x;
    const float* ur = uv + (size_t)bi * 1600;
    const float* vr = ur + 800;
    for (int k = l; k < 800; k += 64) s[k] = gelu_f(ur[k] + vr[k]);
    __syncthreads();
    float a0 = 0.f, a1 = 0.f;
    bool has2 = (l < 2);
    for (int k = 0; k < 800; k++) {
        float sv = s[k];
        a0 += sv * W[k * NE + l];
        if (has2) a1 += sv * W[k * NE + 64 + l];
    }
    lg[l] = a0 + bias[l];
    if (has2) lg[64 + l] = a1 + bias[64 + l];
    __syncthreads();
    if (l == 0) {
        float m = lg[0];
        for (int c = 1; c < NE; c++) m = fmaxf(m, lg[c]);
        float se = 0.f, sl = 0.f, bv = lg[0];
        int am = 0;
        for (int c = 0; c < NE; c++) {
            se += __expf(lg[c] - m);
            sl += lg[c];
            if (lg[c] > bv) { bv = lg[c]; am = c; }
        }
        float lse = m + __logf(se);
        int tgt = labels[(size_t)bi * S128 + i];
        float ce = (0.1f / NE) * (NE * lse - sl) + 0.9f * (lse - lg[tgt]);
        atomicAdd(d_out, ce * (1.f / 128.f));
        int r = bi * S128 + i;
        d_out[1 + r] = (float)am;
        d_out[1 + 65536 + r] = (float)am;
    }
}

// ---------------------------------------------------------------------------
// Fused rs+re logits, NB batches per launch (blockIdx.y). uv stride 1600.
// v3 (BEST-KNOWN for this kernel; R8/R9's 8x16 retile was slower -- occupancy
// loss at 42.5KB LDS outweighed the LDS-traffic win): SINGLE barrier/chunk.
//  - Bs is wave-private by construction: thread ct stages col ct, and wave w
//    only reads cols [w*64, w*64+64). Stage->read is same-wave program order,
//    overwrite happens after that wave's own compute -> NO cross-wave sync.
//  - As (shared M-tile) double-buffered: iteration c stages As[(c+1)&1] while
//    computing from As[c&1]; end-of-iteration barrier separates the WAR pair.
//  - register prefetch retained: W one chunk ahead, u/v two chunks ahead.
__global__ __launch_bounds__(256) void k_logits2(const float* __restrict__ uvb,
                                                 const float* __restrict__ rsW, const float* __restrict__ rsb,
                                                 const float* __restrict__ reW, const float* __restrict__ reb,
                                                 float* __restrict__ L)
{
    __shared__ float As[2][16][68];
    __shared__ float Bs[4][16][68];     // per-wave col slice
    int bi = blockIdx.y;
    const float* base = uvb + (size_t)bi * 128 * 1600;
    float* Lb = L + (size_t)bi * 16384 * 256;
    int il = blockIdx.x >> 1;
    int j0 = (blockIdx.x & 1) * 64;
    const float* urow = base + (size_t)il * 1600;
    int tid = threadIdx.x;
    int wv = tid >> 6, lane = tid & 63;
    int tm = tid & 7, tn = tid >> 3;        // rows tm*8..+7, cols tn*8..+7
    int cln = (tn & 7) * 8;                 // within-wave col offset
    float acc[8][8] = {};
    int hc = (tid < 128) ? tid : (tid - 128);
    const float* Wp = (tid < 128) ? rsW : reW;
    bool cok = hc < NR;
    int kk = tid & 15, rrb = tid >> 4;      // A-staging coords

    // --- prologue ---
    // chunk-0 u/v (consumed immediately into As[0])
    float u0 = urow[kk];
    float v0q[4];
    #pragma unroll
    for (int q = 0; q < 4; q++)
        v0q[q] = base[(size_t)(j0 + rrb + q * 16) * 1600 + 800 + kk];
    // W prefetch: chunk 0 (staged at c=0)
    float wP[16];
    #pragma unroll
    for (int kk2 = 0; kk2 < 16; kk2++)
        wP[kk2] = cok ? Wp[(size_t)kk2 * NR + hc] : 0.f;
    // u/v prefetch: chunk 1 (staged into As[1] at c=0)
    float uP = urow[16 + kk];
    float vP[4];
    #pragma unroll
    for (int q = 0; q < 4; q++)
        vP[q] = base[(size_t)(j0 + rrb + q * 16) * 1600 + 800 + 16 + kk];

    // stage As[0] (chunk 0)
    #pragma unroll
    for (int q = 0; q < 4; q++)
        As[0][kk][rrb + q * 16] = gelu_f(u0 + v0q[q]);
    __syncthreads();

    for (int c = 0; c < 50; ++c) {
        // stage Bs (chunk c) -- wave-private, no barrier needed
        #pragma unroll
        for (int kk2 = 0; kk2 < 16; kk2++)
            Bs[wv][kk2][lane] = wP[kk2];
        // stage As[(c+1)&1] (chunk c+1; last iter writes clamped chunk-0
        // data into a never-again-read buffer)
        #pragma unroll
        for (int q = 0; q < 4; q++)
            As[(c + 1) & 1][kk][rrb + q * 16] = gelu_f(uP + vP[q]);

        // prefetch: W <- chunk c+1, u/v <- chunk c+2 (clamped)
        int k1 = (c + 1 < 50) ? (c + 1) * 16 : 0;
        int k2 = (c + 2 < 50) ? (c + 2) * 16 : 0;
        #pragma unroll
        for (int kk2 = 0; kk2 < 16; kk2++)
            wP[kk2] = cok ? Wp[(size_t)(k1 + kk2) * NR + hc] : 0.f;
        uP = urow[k2 + kk];
        #pragma unroll
        for (int q = 0; q < 4; q++)
            vP[q] = base[(size_t)(j0 + rrb + q * 16) * 1600 + 800 + k2 + kk];

        // compute chunk c from As[c&1] + this wave's Bs slice
        const float (*Ac)[68] = As[c & 1];
        #pragma unroll
        for (int kki = 0; kki < 16; kki++) {
            float4 a0 = *(const float4*)&Ac[kki][tm * 8];
            float4 a1 = *(const float4*)&Ac[kki][tm * 8 + 4];
            float4 b0 = *(const float4*)&Bs[wv][kki][cln];
            float4 b1 = *(const float4*)&Bs[wv][kki][cln + 4];
            float av[8] = {a0.x, a0.y, a0.z, a0.w, a1.x, a1.y, a1.z, a1.w};
            float bvv[8] = {b0.x, b0.y, b0.z, b0.w, b1.x, b1.y, b1.z, b1.w};
            #pragma unroll
            for (int xx = 0; xx < 8; xx++)
                #pragma unroll
                for (int yy = 0; yy < 8; yy++)
                    acc[xx][yy] += av[xx] * bvv[yy];
        }
        __syncthreads();
    }
    int head = tn >> 4;
    const float* bp = head ? reb : rsb;
    #pragma unroll
    for (int xx = 0; xx < 8; xx++) {
        int r = il * S128 + j0 + tm * 8 + xx;
        float* Lr = Lb + (size_t)r * 256 + tn * 8;
        #pragma unroll
        for (int hf = 0; hf < 2; hf++) {
            int c = (tn * 8 + hf * 4) & 127;
            if (c + 3 < NR) {
                float4 o = make_float4(acc[xx][hf*4+0] + bp[c+0], acc[xx][hf*4+1] + bp[c+1],
                                       acc[xx][hf*4+2] + bp[c+2], acc[xx][hf*4+3] + bp[c+3]);
                *(float4*)(Lr + hf * 4) = o;
            } else {
                #pragma unroll
                for (int q = 0; q < 4; q++)
                    if (c + q < NR) Lr[hf * 4 + q] = acc[xx][hf*4+q] + bp[c+q];
            }
        }
    }
}

// CE loss + symmetric argmax, both heads. Handles any number of batches via
// grid size: rr in [0, nbatch*16384), bi = rr>>14 indexes L/labels/results.
__global__ __launch_bounds__(256) void k_loss2(const float* __restrict__ L,
                                               const int* __restrict__ lab0, const int* __restrict__ lab1,
                                               float* __restrict__ res0, float* __restrict__ res1,
                                               float* __restrict__ lossptr)
{
    __shared__ float wsum[4];
    int wv = threadIdx.x >> 6, l = threadIdx.x & 63;
    int rr = blockIdx.x * 4 + wv;
    int bi = rr >> 14;
    int r = rr & 16383;
    int i = r >> 7, j = r & 127;
    size_t bioff = (size_t)bi * 16384;
    float ces = 0.f;
    if (i != j) {
        const float* row  = L + (bioff + r) * 256;
        const float* prow = L + (bioff + ((j << 7) | i)) * 256;
        bool v2 = (l < NR - 64);
        #pragma unroll
        for (int hd = 0; hd < 2; hd++) {
            const float* rw = row + hd * 128;
            const float* pw = prow + hd * 128;
            float x1 = rw[l];
            float x2 = v2 ? rw[l + 64] : -3.4e38f;
            float m = fmaxf(x1, x2);
            #pragma unroll
            for (int s = 32; s; s >>= 1) m = fmaxf(m, __shfl_xor(m, s, 64));
            float se = __expf(x1 - m) + (v2 ? __expf(x2 - m) : 0.f);
            float sl = x1 + (v2 ? x2 : 0.f);
            #pragma unroll
            for (int s = 32; s; s >>= 1) { se += __shfl_xor(se, s, 64); sl += __shfl_xor(sl, s, 64); }
            float lse = m + __logf(se);
            int tgt = (hd ? lab1 : lab0)[bioff + r];
            float lt = rw[tgt];
            ces += (0.1f / NR) * (NR * lse - sl) + 0.9f * (lse - lt);
            float y1 = x1 + pw[l];
            float y2 = v2 ? (x2 + pw[l + 64]) : -3.4e38f;
            float bv; int bidx;
            if (y2 > y1) { bv = y2; bidx = l + 64; } else { bv = y1; bidx = l; }
            #pragma unroll
            for (int s = 32; s; s >>= 1) {
                float ov = __shfl_xor(bv, s, 64);
                int oi = __shfl_xor(bidx, s, 64);
                if (ov > bv || (ov == bv && oi < bidx)) { bv = ov; bidx = oi; }
            }
            if (l == 0) (hd ? res1 : res0)[bioff + r] = (float)bidx;
        }
    }
    if (l == 0) wsum[wv] = ces;
    __syncthreads();
    if (threadIdx.x == 0) {
        float s = (wsum[0] + wsum[1] + wsum[2] + wsum[3]) * (1.f / 16256.f);
        atomicAdd(lossptr, s);
    }
}

// ---------------------------------------------------------------------------
extern "C" void kernel_launch(void* const* d_in, const int* in_sizes, int n_in,
                              void* d_out, int out_size, void* d_ws, size_t ws_size,
                              hipStream_t stream)
{
    (void)in_sizes; (void)n_in; (void)out_size;
    const float* bert  = (const float*)d_in[0];
    const int*   pids  = (const int*)d_in[1];
    const int*   esrc  = (const int*)d_in[2];
    const int*   edst  = (const int*)d_in[3];
    const int*   slab  = (const int*)d_in[4];
    const int*   elab  = (const int*)d_in[5];
    const float* ptab  = (const float*)d_in[6];
    const float* Wih_f = (const float*)d_in[7];
    const float* Whh_f = (const float*)d_in[8];
    const float* bl_f  = (const float*)d_in[9];
    const float* Wih_b = (const float*)d_in[10];
    const float* Whh_b = (const float*)d_in[11];
    const float* bl_b  = (const float*)d_in[12];
    const float* fcW   = (const float*)d_in[13];
    const float* fcb   = (const float*)d_in[14];
    const float* tW    = (const float*)d_in[15];
    const float* tb    = (const float*)d_in[16];
    const float* gatW  = (const float*)d_in[17];
    const float* asrc  = (const float*)d_in[18];
    const float* adst  = (const float*)d_in[19];
    const float* gbias = (const float*)d_in[20];
    const float* trigW = (const float*)d_in[21];
    const float* trigb = (const float*)d_in[22];
    const float* rsW   = (const float*)d_in[23];
    const float* rsb   = (const float*)d_in[24];
    const float* reW   = (const float*)d_in[25];
    const float* reb   = (const float*)d_in[26];
    float* out = (float*)d_out;

    float* ws = (float*)d_ws;
    size_t off = 0;
    auto alloc = [&](size_t n) { float* p = ws + off; off += (n + 255) & ~(size_t)255; return p; };
    float* uv    = alloc((size_t)512 * 1600);     // live late (trig/logits)
    float* R     = ws + off;                      // overlay region
    size_t roff = 0;
    auto ralloc = [&](size_t n) { float* p = R + roff; roff += (n + 255) & ~(size_t)255; return p; };
    float* xW   = ralloc((size_t)516 * 6400);
    float* lstm = ralloc((size_t)516 * 1600);
    float* xg   = ralloc(516 * 800);
    float* h1   = ralloc(512 * 800);
    float* g1   = ralloc(512 * 800);
    float* g2   = ralloc(512 * 800);
    float* hpk  = ralloc((size_t)2 * 129 * 100 * 32);  // packed h exchange; dead before Lbuf
    float* Lbuf = R;   // overlays dead temps

    hipMemsetAsync(d_out, 0, 4, stream);                 // loss accumulator
    // sentinel-fill the h exchange: 0x7F7F7F7F = 3.39e38 (|v| >= 1.5 => not yet written).
    // Stream-ordered before k_lstm, so workspace poison can never look valid.
    hipMemsetAsync(hpk, 0x7F, (size_t)2 * 129 * 100 * 32 * sizeof(float), stream);

    // merged gate-input precompute with fused embed
    k_gemm_wih<<<dim3(9, 100), 256, 0, stream>>>(bert, pids, ptab, Wih_f, Wih_b, bl_f, bl_b, xW);

    k_lstm<<<2 * NWGD, 256, 0, stream>>>(xW, Whh_f, Whh_b, lstm, hpk);

    // xg = embed(x) + relu(lstm @ fcW + fcb)
    k_gemm_fc<<<dim3(9, 13), 256, 0, stream>>>(lstm, fcW, fcb, bert, pids, ptab, xg);

    // GAT layer 1 (input = xg[:,1:,:] view)
    k_gemm<1, 0, 0><<<dim3(8, 13), 256, 0, stream>>>(xg, gatW, nullptr, nullptr, h1, 512, 800, 800);
    k_gat_fused<1><<<32, 512, 0, stream>>>(esrc, edst, h1, asrc, adst, gbias, xg, g1);
    // GAT layer 2
    k_gemm<0, 0, 0><<<dim3(8, 13), 256, 0, stream>>>(g1, gatW, nullptr, nullptr, h1, 512, 800, 800);
    k_gat_fused<0><<<32, 512, 0, stream>>>(esrc, edst, h1, asrc, adst, gbias, g1, g2);

    // merged table split: uv[512][1600] (u | v)
    k_gemm_uv<<<dim3(8, 25), 256, 0, stream>>>(g2, tW, tb, uv);

    // trig head (diag)
    k_trig<<<512, 64, 0, stream>>>(uv, trigW, trigb, slab, out);

    // rs+re heads: single 4-batch pass if the workspace can hold the full L
    // buffer (4 x 16384 x 256 floats over the R overlay), else 2x2-batch.
    size_t need4 = (off + (size_t)4 * 16384 * 256) * sizeof(float);
    if (ws_size >= need4) {
        k_logits2<<<dim3(256, 4), 256, 0, stream>>>(uv, rsW, rsb, reW, reb, Lbuf);
        k_loss2<<<16384, 256, 0, stream>>>(Lbuf, slab, elab,
                                           out + 1, out + 1 + 65536, out);
    } else {
        for (int bp = 0; bp < 2; bp++) {
            k_logits2<<<dim3(256, 2), 256, 0, stream>>>(uv + (size_t)bp * 2 * 128 * 1600,
                                                        rsW, rsb, reW, reb, Lbuf);
            k_loss2<<<8192, 256, 0, stream>>>(Lbuf,
                                              slab + (size_t)bp * 2 * 16384, elab + (size_t)bp * 2 * 16384,
                                              out + 1 + (size_t)bp * 2 * 16384,
                                              out + 1 + 65536 + (size_t)bp * 2 * 16384, out);
        }
    }
}